// Round 11
// baseline (865.436 us; speedup 1.0000x reference)
//
#include <hip/hip_runtime.h>
#include <math.h>

#define N_NODES 100000
#define N_EDGES 3200000
#define KH 48            // K*H active channels
#define FDIM 64          // padded feature row stride (128 B, line-aligned)
#define NH 16            // H
#define BN_EPS 1e-5f
#define NBUCK 196        // ceil(100000/512) buckets of 512 nodes
#define BSHIFT 9
#define BMASK 511
#define EPB 16384        // edges per block in bucket kernels
#define NBLK1 196        // ceil(N_EDGES/EPB)
#define FIX 16777216.0f  // 2^24 fixed point for degree sums

typedef unsigned long long u64;
typedef unsigned int u32;
typedef unsigned short u16;

__device__ __forceinline__ u16 f2bf(float f) {
  u32 b = __float_as_uint(f);
  b += 0x7FFFu + ((b >> 16) & 1u);   // RNE
  return (u16)(b >> 16);
}
__device__ __forceinline__ float bf2f(u32 s) {
  return __uint_as_float(s << 16);
}

// ---------------- K1: per-block LDS bucket histogram -> global totals -------
__global__ __launch_bounds__(256) void bucket_count_kernel(
    const int* __restrict__ col, u32* __restrict__ btot /* stride 8 */) {
  __shared__ u32 bins[NBUCK];
  for (int t = threadIdx.x; t < NBUCK; t += 256) bins[t] = 0;
  __syncthreads();
  int eb = blockIdx.x * EPB;
  for (int it = 0; it < EPB / 256; ++it) {
    int e = eb + it * 256 + threadIdx.x;
    if (e < N_EDGES) atomicAdd(&bins[col[e] >> BSHIFT], 1u);
  }
  __syncthreads();
  for (int t = threadIdx.x; t < NBUCK; t += 256)
    if (bins[t]) atomicAdd(&btot[t * 8], bins[t]);
}

// ---------------- K2: scan bucket totals -> starts, init cursors ------------
__global__ __launch_bounds__(256) void bucket_scan_kernel(
    const u32* __restrict__ btot, u32* __restrict__ bstart, u32* __restrict__ gcur,
    int* __restrict__ offs) {
  __shared__ u32 sh[256];
  int t = threadIdx.x;
  u32 v = (t < NBUCK) ? btot[t * 8] : 0;
  sh[t] = v;
  __syncthreads();
  for (int d = 1; d < 256; d <<= 1) {
    u32 u = (t >= d) ? sh[t - d] : 0;
    __syncthreads();
    sh[t] += u;
    __syncthreads();
  }
  if (t < NBUCK) { u32 s = sh[t] - v; bstart[t] = s; gcur[t * 8] = s; }
  if (t == NBUCK) bstart[NBUCK] = N_EDGES;
  if (t == 0) offs[N_NODES] = N_EDGES;
}

// ---------------- K3: scatter edges into bucket-major order -----------------
__global__ __launch_bounds__(256) void bucket_scatter_kernel(
    const int* __restrict__ row, const int* __restrict__ col,
    const float* __restrict__ ea, u32* __restrict__ gcur,
    int2* __restrict__ bucketed) {
  __shared__ u32 bins[NBUCK];
  __shared__ u32 base[NBUCK];
  __shared__ u16 rnk[EPB];
  for (int t = threadIdx.x; t < NBUCK; t += 256) bins[t] = 0;
  __syncthreads();
  int eb = blockIdx.x * EPB;
  for (int it = 0; it < EPB / 256; ++it) {
    int i = it * 256 + threadIdx.x;
    int e = eb + i;
    if (e < N_EDGES) rnk[i] = (u16)atomicAdd(&bins[col[e] >> BSHIFT], 1u);
  }
  __syncthreads();
  for (int t = threadIdx.x; t < NBUCK; t += 256) {
    u32 c = bins[t];
    if (c) base[t] = atomicAdd(&gcur[t * 8], c);
  }
  __syncthreads();
  for (int it = 0; it < EPB / 256; ++it) {
    int i = it * 256 + threadIdx.x;
    int e = eb + i;
    if (e < N_EDGES) {
      int c = col[e];
      int bkt = c >> BSHIFT, cl = c & BMASK;
      u32 pos = base[bkt] + (u32)rnk[i];
      bucketed[pos] = make_int2((cl << 17) | row[e], __float_as_int(ea[e]));
    }
  }
}

// ---------------- P2a: per-bucket node counts -> offs, dinv, zx -------------
__global__ __launch_bounds__(1024) void node_offs_kernel(
    const int2* __restrict__ bucketed, const u32* __restrict__ bstart,
    const float* __restrict__ x,
    int* __restrict__ offs, float* __restrict__ dinv, u16* __restrict__ zx) {
  __shared__ u32 cnt[512];
  __shared__ u32 degf[512];
  int t = threadIdx.x;
  if (t < 512) { cnt[t] = 0; degf[t] = 0; }
  __syncthreads();
  int b = blockIdx.x;
  u32 s = bstart[b], e = bstart[b + 1];
  for (u32 i = s + t; i < e; i += 1024) {
    int2 v = bucketed[i];
    int cl = (v.x >> 17) & BMASK;
    atomicAdd(&cnt[cl], 1u);
    atomicAdd(&degf[cl], (u32)(__int_as_float(v.y) * FIX));
  }
  __syncthreads();
  u32 v0 = (t < 512) ? cnt[t] : 0;
  for (int d = 1; d < 512; d <<= 1) {
    u32 u = (t < 512 && t >= d) ? cnt[t - d] : 0;
    __syncthreads();
    if (t < 512) cnt[t] += u;
    __syncthreads();
  }
  int n = b * 512 + t;
  if (t < 512 && n < N_NODES) {
    offs[n] = (int)(s + cnt[t] - v0);  // exclusive
    float dg = (float)degf[t] * (1.0f / FIX);
    float dv = dg > 0.f ? rsqrtf(fmaxf(dg, 1e-12f)) : 0.f;
    dinv[n] = dv;
    zx[n] = f2bf(x[n] * dv);
  }
}

// ---------------- P2b: packed 4B CSR: (src<<15) | bf16(ea) ------------------
__global__ __launch_bounds__(1024) void csr_fill_kernel(
    const int2* __restrict__ bucketed, const u32* __restrict__ bstart,
    const int* __restrict__ offs, u32* __restrict__ csr) {
  __shared__ u32 cur[512];
  int t = threadIdx.x;
  int b = blockIdx.x;
  int n = b * 512 + t;
  if (t < 512) cur[t] = (n < N_NODES) ? (u32)offs[n] : 0;
  __syncthreads();
  u32 s = bstart[b], e = bstart[b + 1];
  for (u32 i = s + t; i < e; i += 1024) {
    int2 v = bucketed[i];
    int cl = (v.x >> 17) & BMASK;
    u32 r = (u32)(v.x & 0x1FFFF);
    u16 w = f2bf(__int_as_float(v.y));   // ea >= 0 -> sign bit 0, w < 0x8000
    u32 pos = atomicAdd(&cur[cl], 1u);
    csr[pos] = (r << 15) | (u32)w;
  }
}

// ---------------- layer-1 scalar propagate: s = Ahat * x --------------------
// 16-lane group per node, lanes split edges.
__global__ __launch_bounds__(256) void sprop_kernel(
    const u32* __restrict__ csr, const int* __restrict__ offs,
    const u16* __restrict__ zx, const float* __restrict__ dinv,
    float* __restrict__ sbuf) {
  int t = blockIdx.x * 256 + threadIdx.x;
  int n = t >> 4, sub = t & 15;
  float a = 0.f;
  int s = offs[n], e = offs[n + 1];
  for (int i = s + sub; i < e; i += 16) {
    u32 ee = __builtin_nontemporal_load(&csr[i]);
    a += bf2f(ee & 0x7FFFu) * bf2f((u32)zx[ee >> 15]);
  }
#pragma unroll
  for (int o = 8; o; o >>= 1) a += __shfl_xor(a, o, 64);
  if (sub == 0) sbuf[n] = dinv[n] * a;
}

// ---------------- layer-1 epilogue + transform -> [N][FDIM] bf16 ------------
// out1 = relu(s*w1i + x*w1r + b1); store (out1 @ w1) * dinv as bf16.
__global__ __launch_bounds__(256) void conv1_mid_kernel(
    const float* __restrict__ sbuf, const float* __restrict__ x,
    const float* __restrict__ dinv,
    const float* __restrict__ w1i, const float* __restrict__ w1r,
    const float* __restrict__ b1, const float* __restrict__ w1,
    u16* __restrict__ tout) {
  int t = blockIdx.x * 256 + threadIdx.x;
  int n = t >> 4, c = t & 15;
  int base = (threadIdx.x & 63) & 48;
  float sn = sbuf[n], xn = x[n], dn = dinv[n];
#pragma unroll
  for (int k = 0; k < 3; ++k) {
    float u = fmaxf(sn * w1i[k * 16 + c] + xn * w1r[k * 16 + c] + b1[k * 16 + c], 0.f);
    float tf = 0.f;
#pragma unroll
    for (int f = 0; f < 16; ++f) tf += __shfl(u, base + f, 64) * w1[k * 256 + f * 16 + c];
    tout[(size_t)n * FDIM + k * 16 + c] = f2bf(tf * dn);
  }
}

// ---------------- conv1 propagate, all 3 stacks combined --------------------
// wave per node, lane = channel, 48 active; rows 128 B line-aligned.
// UNMASKED unroll-16 main loop, then 8/4/scalar ladder. No cndmask on
// addresses (R7 failure mode). nt CSR loads (stream, don't cache).
__global__ __launch_bounds__(256) void conv1_prop_kernel(
    const u16* __restrict__ tin, u16* __restrict__ tout, float* __restrict__ hbuf,
    const u32* __restrict__ csr, const int* __restrict__ offs,
    const float* __restrict__ dinv, const float* __restrict__ x,
    const float* __restrict__ w1r, const float* __restrict__ b1,
    const float* __restrict__ w1, int do_t) {
  int lane = threadIdx.x & 63;
  int wid = (blockIdx.x * blockDim.x + threadIdx.x) >> 6;
  int nw = (gridDim.x * blockDim.x) >> 6;
  int c = lane;
  bool act = c < KH;
  float rb = act ? w1r[c] : 0.f;
  float bb = act ? b1[c] : 0.f;
  float wreg[16];
  if (do_t) {
    int k = c >> 4, o = c & 15;
    if (act) {
#pragma unroll
      for (int f = 0; f < 16; ++f) wreg[f] = w1[k * 256 + f * 16 + o];
    } else {
#pragma unroll
      for (int f = 0; f < 16; ++f) wreg[f] = 0.f;
    }
  }
  for (int n = wid; n < N_NODES; n += nw) {
    int nu = __builtin_amdgcn_readfirstlane(n);
    int s = offs[nu], e = offs[nu + 1];
    float acc = 0.f;
    int i = s;
    for (; i + 16 <= e; i += 16) {
      u32 ee[16];
#pragma unroll
      for (int k = 0; k < 16; ++k) ee[k] = __builtin_nontemporal_load(&csr[i + k]);
      float vv[16];
#pragma unroll
      for (int k = 0; k < 16; ++k)
        vv[k] = act ? bf2f((u32)tin[(ee[k] >> 15) * FDIM + c]) : 0.f;
#pragma unroll
      for (int k = 0; k < 16; ++k) acc += bf2f(ee[k] & 0x7FFFu) * vv[k];
    }
    for (; i + 8 <= e; i += 8) {
      u32 ee[8];
#pragma unroll
      for (int k = 0; k < 8; ++k) ee[k] = __builtin_nontemporal_load(&csr[i + k]);
      float vv[8];
#pragma unroll
      for (int k = 0; k < 8; ++k)
        vv[k] = act ? bf2f((u32)tin[(ee[k] >> 15) * FDIM + c]) : 0.f;
#pragma unroll
      for (int k = 0; k < 8; ++k) acc += bf2f(ee[k] & 0x7FFFu) * vv[k];
    }
    for (; i + 4 <= e; i += 4) {
      u32 e0 = __builtin_nontemporal_load(&csr[i]);
      u32 e1 = __builtin_nontemporal_load(&csr[i + 1]);
      u32 e2 = __builtin_nontemporal_load(&csr[i + 2]);
      u32 e3 = __builtin_nontemporal_load(&csr[i + 3]);
      float v0 = 0.f, v1 = 0.f, v2 = 0.f, v3 = 0.f;
      if (act) {
        v0 = bf2f((u32)tin[(e0 >> 15) * FDIM + c]);
        v1 = bf2f((u32)tin[(e1 >> 15) * FDIM + c]);
        v2 = bf2f((u32)tin[(e2 >> 15) * FDIM + c]);
        v3 = bf2f((u32)tin[(e3 >> 15) * FDIM + c]);
      }
      acc += bf2f(e0 & 0x7FFFu) * v0 + bf2f(e1 & 0x7FFFu) * v1 +
             bf2f(e2 & 0x7FFFu) * v2 + bf2f(e3 & 0x7FFFu) * v3;
    }
    for (; i < e; ++i) {
      u32 ee = __builtin_nontemporal_load(&csr[i]);
      if (act) acc += bf2f(ee & 0x7FFFu) * bf2f((u32)tin[(ee >> 15) * FDIM + c]);
    }
    float dn = dinv[nu];
    float u = fmaxf(acc * dn + x[nu] * rb + bb, 0.f);
    if (do_t) {
      float tf = 0.f;
      int base = c & 48;
#pragma unroll
      for (int f = 0; f < 16; ++f) tf += __shfl(u, base + f, 64) * wreg[f];
      if (act) tout[(size_t)nu * FDIM + c] = f2bf(tf * dn);
    } else {
      float m1v = __shfl(u, lane + 16, 64);
      float m2v = __shfl(u, lane + 32, 64);
      if (lane < NH) hbuf[(size_t)nu * NH + lane] = (u + m1v + m2v) * (1.f / 3.f);
    }
  }
}

// ---------------- BN stats over hbuf [N,16] ---------------------------------
__global__ __launch_bounds__(256) void bn_stats_kernel(
    const float* __restrict__ h, double* __restrict__ stats) {
  __shared__ float ssum[NH], ssq[NH];
  int tid = threadIdx.x;
  if (tid < NH) { ssum[tid] = 0.f; ssq[tid] = 0.f; }
  __syncthreads();
  int n = blockIdx.x * blockDim.x + tid;
  bool valid = n < N_NODES;
  const float4* p = (const float4*)(h + (size_t)(valid ? n : 0) * NH);
  float hv[NH];
#pragma unroll
  for (int q = 0; q < 4; ++q) {
    float4 v = valid ? p[q] : make_float4(0.f, 0.f, 0.f, 0.f);
    hv[q * 4 + 0] = v.x; hv[q * 4 + 1] = v.y; hv[q * 4 + 2] = v.z; hv[q * 4 + 3] = v.w;
  }
#pragma unroll
  for (int f = 0; f < NH; ++f) {
    float s = hv[f], q = hv[f] * hv[f];
    for (int o = 32; o; o >>= 1) { s += __shfl_xor(s, o, 64); q += __shfl_xor(q, o, 64); }
    if ((tid & 63) == 0) { atomicAdd(&ssum[f], s); atomicAdd(&ssq[f], q); }
  }
  __syncthreads();
  if (tid < NH) {
    atomicAdd(&stats[tid], (double)ssum[tid]);
    atomicAdd(&stats[NH + tid], (double)ssq[tid]);
  }
}

__global__ __launch_bounds__(64) void bn_final_kernel(
    const double* __restrict__ stats, const float* __restrict__ g,
    const float* __restrict__ b, float* __restrict__ sc, float* __restrict__ sh) {
  int f = threadIdx.x;
  if (f < NH) {
    double mu = stats[f] / (double)N_NODES;
    double var = stats[NH + f] / (double)N_NODES - mu * mu;
    float scale = g[f] * (float)(1.0 / sqrt(var + (double)BN_EPS));
    sc[f] = scale;
    sh[f] = b[f] - (float)mu * scale;
  }
}

// ---------------- conv2 init: BN-apply + relu + init/root dots --------------
__global__ __launch_bounds__(256) void conv2_init_kernel(
    const float* __restrict__ h, const float* __restrict__ sc, const float* __restrict__ sh,
    const float* __restrict__ dinv,
    const float* __restrict__ w2i, const float* __restrict__ w2r, const float* __restrict__ b2,
    float* __restrict__ P, float* __restrict__ R) {
  int n = blockIdx.x * blockDim.x + threadIdx.x;
  if (n >= N_NODES) return;
  float u[NH];
#pragma unroll
  for (int f = 0; f < NH; ++f) u[f] = fmaxf(h[(size_t)n * NH + f] * sc[f] + sh[f], 0.f);
  float dn = dinv[n];
#pragma unroll
  for (int k = 0; k < 3; ++k) {
    float r = b2[k], o = 0.f;
#pragma unroll
    for (int f = 0; f < NH; ++f) {
      r += u[f] * w2r[k * NH + f];
      o += u[f] * w2i[k * NH + f];
    }
    R[n * 4 + k] = r;
    P[n * 4 + k] = o * dn;
  }
  R[n * 4 + 3] = 0.f;
  P[n * 4 + 3] = 0.f;
}

// ---------------- conv2 propagate: 16-lane groups, packed CSR ---------------
__global__ __launch_bounds__(256) void conv2_prop_kernel(
    const float* __restrict__ in4, float* __restrict__ out4, float* __restrict__ y,
    const u32* __restrict__ csr, const int* __restrict__ offs,
    const float* __restrict__ dinv,
    const float* __restrict__ R, const float* __restrict__ w2,
    int scale_w2, int final_out) {
  int t = blockIdx.x * 256 + threadIdx.x;
  int n = t >> 4, sub = t & 15;
  float m0 = 1.f, m1 = 1.f, m2 = 1.f;
  if (scale_w2) { m0 = w2[0]; m1 = w2[1]; m2 = w2[2]; }
  int s = offs[n], e = offs[n + 1];
  float a0 = 0.f, a1 = 0.f, a2 = 0.f;
  for (int i = s + sub; i < e; i += 16) {
    u32 ee = __builtin_nontemporal_load(&csr[i]);
    float w = bf2f(ee & 0x7FFFu);
    const float4 v = *(const float4*)(in4 + (size_t)(ee >> 15) * 4);
    a0 += w * v.x;
    a1 += w * v.y;
    a2 += w * v.z;
  }
#pragma unroll
  for (int o = 8; o; o >>= 1) {
    a0 += __shfl_xor(a0, o, 64);
    a1 += __shfl_xor(a1, o, 64);
    a2 += __shfl_xor(a2, o, 64);
  }
  if (sub == 0) {
    float dn = dinv[n];
    a0 = a0 * dn * m0 + R[n * 4 + 0];
    a1 = a1 * dn * m1 + R[n * 4 + 1];
    a2 = a2 * dn * m2 + R[n * 4 + 2];
    if (final_out) {
      float sm = (a0 + a1 + a2) * (1.f / 3.f);
      y[n] = 1.f / (1.f + expf(-sm));
    } else {
      out4[n * 4 + 0] = a0 * dn;
      out4[n * 4 + 1] = a1 * dn;
      out4[n * 4 + 2] = a2 * dn;
      out4[n * 4 + 3] = 0.f;
    }
  }
}

extern "C" void kernel_launch(void* const* d_in, const int* in_sizes, int n_in,
                              void* d_out, int out_size, void* d_ws, size_t ws_size,
                              hipStream_t stream) {
  const float* x   = (const float*)d_in[0];
  const int*   ei  = (const int*)d_in[1];
  const float* ea  = (const float*)d_in[2];
  // d_in[3] = batch (unused)
  const float* w1i = (const float*)d_in[4];
  const float* w1  = (const float*)d_in[5];
  const float* w1r = (const float*)d_in[6];
  const float* b1  = (const float*)d_in[7];
  const float* bng = (const float*)d_in[8];
  const float* bnb = (const float*)d_in[9];
  const float* w2i = (const float*)d_in[10];
  const float* w2  = (const float*)d_in[11];
  const float* w2r = (const float*)d_in[12];
  const float* b2  = (const float*)d_in[13];
  float* y = (float*)d_out;

  const int* row = ei;
  const int* col = ei + N_EDGES;

  char* ws = (char*)d_ws;
  size_t off = 0;
  auto alloc = [&](size_t bytes) -> char* {
    char* p = ws + off;
    off += (bytes + 255) & ~(size_t)255;
    return p;
  };
  u32*    btot   = (u32*)alloc((size_t)NBUCK * 8 * 4);
  u32*    gcur   = (u32*)alloc((size_t)NBUCK * 8 * 4);
  u32*    bstart = (u32*)alloc((size_t)(NBUCK + 1) * 4);
  int*    offs   = (int*)alloc((size_t)(N_NODES + 1) * 4);
  float*  dinv   = (float*)alloc((size_t)N_NODES * 4);
  u16*    zx     = (u16*)alloc((size_t)N_NODES * 2);
  float*  sbuf   = (float*)alloc((size_t)N_NODES * 4);
  double* stats  = (double*)alloc(32 * 8);
  float*  bnsc   = (float*)alloc(16 * 4);
  float*  bnsh   = (float*)alloc(16 * 4);
  int2*   bucketed = (int2*)alloc((size_t)N_EDGES * 8);
  u32*    csr    = (u32*)alloc((size_t)N_EDGES * 4);
  u16*    tA     = (u16*)alloc((size_t)N_NODES * FDIM * 2);
  u16*    tB     = (u16*)alloc((size_t)N_NODES * FDIM * 2);
  float*  hbuf   = (float*)alloc((size_t)N_NODES * NH * 4);
  float*  P2     = (float*)alloc((size_t)N_NODES * 4 * 4);
  float*  Q2     = (float*)alloc((size_t)N_NODES * 4 * 4);
  float*  R2     = (float*)alloc((size_t)N_NODES * 4 * 4);
  (void)ws_size; (void)in_sizes; (void)n_in; (void)out_size;

  hipMemsetAsync(btot, 0, (size_t)NBUCK * 8 * 4, stream);
  hipMemsetAsync(stats, 0, 32 * 8, stream);

  bucket_count_kernel<<<NBLK1, 256, 0, stream>>>(col, btot);
  bucket_scan_kernel<<<1, 256, 0, stream>>>(btot, bstart, gcur, offs);
  bucket_scatter_kernel<<<NBLK1, 256, 0, stream>>>(row, col, ea, gcur, bucketed);
  node_offs_kernel<<<NBUCK, 1024, 0, stream>>>(bucketed, bstart, x, offs, dinv, zx);
  csr_fill_kernel<<<NBUCK, 1024, 0, stream>>>(bucketed, bstart, offs, csr);

  const int NPB = 6250;  // N_NODES*16/256 exactly
  // conv1 layer 1 (rank-1 collapse): scalar prop + dense epilogue -> tA
  sprop_kernel<<<NPB, 256, 0, stream>>>(csr, offs, zx, dinv, sbuf);
  conv1_mid_kernel<<<NPB, 256, 0, stream>>>(sbuf, x, dinv, w1i, w1r, b1, w1, tA);
  // conv1 layers 2-4: combined 3-stack propagation; 25000 waves = 4 nodes/wave
  conv1_prop_kernel<<<6250, 256, 0, stream>>>(tA, tB, nullptr, csr, offs, dinv, x, w1r, b1, w1, 1);
  conv1_prop_kernel<<<6250, 256, 0, stream>>>(tB, tA, nullptr, csr, offs, dinv, x, w1r, b1, w1, 1);
  conv1_prop_kernel<<<6250, 256, 0, stream>>>(tA, nullptr, hbuf, csr, offs, dinv, x, w1r, b1, w1, 0);

  bn_stats_kernel<<<(N_NODES + 255) / 256, 256, 0, stream>>>(hbuf, stats);
  bn_final_kernel<<<1, 64, 0, stream>>>(stats, bng, bnb, bnsc, bnsh);
  conv2_init_kernel<<<(N_NODES + 255) / 256, 256, 0, stream>>>(
      hbuf, bnsc, bnsh, dinv, w2i, w2r, b2, P2, R2);

  conv2_prop_kernel<<<NPB, 256, 0, stream>>>(P2, Q2, nullptr, csr, offs, dinv, R2, w2, 0, 0);
  conv2_prop_kernel<<<NPB, 256, 0, stream>>>(Q2, P2, nullptr, csr, offs, dinv, R2, w2, 1, 0);
  conv2_prop_kernel<<<NPB, 256, 0, stream>>>(P2, Q2, nullptr, csr, offs, dinv, R2, w2, 1, 0);
  conv2_prop_kernel<<<NPB, 256, 0, stream>>>(Q2, P2, y, csr, offs, dinv, R2, w2, 1, 1);
}

// Round 12
// 549.782 us; speedup vs baseline: 1.5741x; 1.5741x over previous
//
#include <hip/hip_runtime.h>
#include <math.h>

#define N_NODES 100000
#define N_EDGES 3200000
#define KH 48            // K*H active channels
#define FDIM 64          // padded feature row stride (128 B, line-aligned)
#define NH 16            // H
#define BN_EPS 1e-5f
#define NBUCK 196        // ceil(100000/512) buckets of 512 nodes
#define BSHIFT 9
#define BMASK 511
#define EPB 16384        // edges per block in bucket kernels
#define NBLK1 196        // ceil(N_EDGES/EPB)
#define FIX 16777216.0f  // 2^24 fixed point for degree sums

typedef unsigned long long u64;
typedef unsigned int u32;
typedef unsigned short u16;

__device__ __forceinline__ u16 f2bf(float f) {
  u32 b = __float_as_uint(f);
  b += 0x7FFFu + ((b >> 16) & 1u);   // RNE
  return (u16)(b >> 16);
}
__device__ __forceinline__ float bf2f(u32 s) {
  return __uint_as_float(s << 16);
}

// ---------------- K1: per-block LDS bucket histogram -> global totals -------
__global__ __launch_bounds__(256) void bucket_count_kernel(
    const int* __restrict__ col, u32* __restrict__ btot /* stride 8 */) {
  __shared__ u32 bins[NBUCK];
  for (int t = threadIdx.x; t < NBUCK; t += 256) bins[t] = 0;
  __syncthreads();
  int eb = blockIdx.x * EPB;
  for (int it = 0; it < EPB / 256; ++it) {
    int e = eb + it * 256 + threadIdx.x;
    if (e < N_EDGES) atomicAdd(&bins[col[e] >> BSHIFT], 1u);
  }
  __syncthreads();
  for (int t = threadIdx.x; t < NBUCK; t += 256)
    if (bins[t]) atomicAdd(&btot[t * 8], bins[t]);
}

// ---------------- K2: scan bucket totals -> starts, init cursors ------------
__global__ __launch_bounds__(256) void bucket_scan_kernel(
    const u32* __restrict__ btot, u32* __restrict__ bstart, u32* __restrict__ gcur,
    int* __restrict__ offs) {
  __shared__ u32 sh[256];
  int t = threadIdx.x;
  u32 v = (t < NBUCK) ? btot[t * 8] : 0;
  sh[t] = v;
  __syncthreads();
  for (int d = 1; d < 256; d <<= 1) {
    u32 u = (t >= d) ? sh[t - d] : 0;
    __syncthreads();
    sh[t] += u;
    __syncthreads();
  }
  if (t < NBUCK) { u32 s = sh[t] - v; bstart[t] = s; gcur[t * 8] = s; }
  if (t == NBUCK) bstart[NBUCK] = N_EDGES;
  if (t == 0) offs[N_NODES] = N_EDGES;
}

// ---------------- K3: scatter edges into bucket-major order -----------------
__global__ __launch_bounds__(256) void bucket_scatter_kernel(
    const int* __restrict__ row, const int* __restrict__ col,
    const float* __restrict__ ea, u32* __restrict__ gcur,
    int2* __restrict__ bucketed) {
  __shared__ u32 bins[NBUCK];
  __shared__ u32 base[NBUCK];
  __shared__ u16 rnk[EPB];
  for (int t = threadIdx.x; t < NBUCK; t += 256) bins[t] = 0;
  __syncthreads();
  int eb = blockIdx.x * EPB;
  for (int it = 0; it < EPB / 256; ++it) {
    int i = it * 256 + threadIdx.x;
    int e = eb + i;
    if (e < N_EDGES) rnk[i] = (u16)atomicAdd(&bins[col[e] >> BSHIFT], 1u);
  }
  __syncthreads();
  for (int t = threadIdx.x; t < NBUCK; t += 256) {
    u32 c = bins[t];
    if (c) base[t] = atomicAdd(&gcur[t * 8], c);
  }
  __syncthreads();
  for (int it = 0; it < EPB / 256; ++it) {
    int i = it * 256 + threadIdx.x;
    int e = eb + i;
    if (e < N_EDGES) {
      int c = col[e];
      int bkt = c >> BSHIFT, cl = c & BMASK;
      u32 pos = base[bkt] + (u32)rnk[i];
      bucketed[pos] = make_int2((cl << 17) | row[e], __float_as_int(ea[e]));
    }
  }
}

// ---------------- P2a: per-bucket node counts -> offs, dinv, zx -------------
__global__ __launch_bounds__(1024) void node_offs_kernel(
    const int2* __restrict__ bucketed, const u32* __restrict__ bstart,
    const float* __restrict__ x,
    int* __restrict__ offs, float* __restrict__ dinv, u16* __restrict__ zx) {
  __shared__ u32 cnt[512];
  __shared__ u32 degf[512];
  int t = threadIdx.x;
  if (t < 512) { cnt[t] = 0; degf[t] = 0; }
  __syncthreads();
  int b = blockIdx.x;
  u32 s = bstart[b], e = bstart[b + 1];
  for (u32 i = s + t; i < e; i += 1024) {
    int2 v = bucketed[i];
    int cl = (v.x >> 17) & BMASK;
    atomicAdd(&cnt[cl], 1u);
    atomicAdd(&degf[cl], (u32)(__int_as_float(v.y) * FIX));
  }
  __syncthreads();
  u32 v0 = (t < 512) ? cnt[t] : 0;
  for (int d = 1; d < 512; d <<= 1) {
    u32 u = (t < 512 && t >= d) ? cnt[t - d] : 0;
    __syncthreads();
    if (t < 512) cnt[t] += u;
    __syncthreads();
  }
  int n = b * 512 + t;
  if (t < 512 && n < N_NODES) {
    offs[n] = (int)(s + cnt[t] - v0);  // exclusive
    float dg = (float)degf[t] * (1.0f / FIX);
    float dv = dg > 0.f ? rsqrtf(fmaxf(dg, 1e-12f)) : 0.f;
    dinv[n] = dv;
    zx[n] = f2bf(x[n] * dv);
  }
}

// ---------------- P2b: packed 4B CSR: (src<<15) | bf16(ea) ------------------
__global__ __launch_bounds__(1024) void csr_fill_kernel(
    const int2* __restrict__ bucketed, const u32* __restrict__ bstart,
    const int* __restrict__ offs, u32* __restrict__ csr) {
  __shared__ u32 cur[512];
  int t = threadIdx.x;
  int b = blockIdx.x;
  int n = b * 512 + t;
  if (t < 512) cur[t] = (n < N_NODES) ? (u32)offs[n] : 0;
  __syncthreads();
  u32 s = bstart[b], e = bstart[b + 1];
  for (u32 i = s + t; i < e; i += 1024) {
    int2 v = bucketed[i];
    int cl = (v.x >> 17) & BMASK;
    u32 r = (u32)(v.x & 0x1FFFF);
    u16 w = f2bf(__int_as_float(v.y));   // ea >= 0 -> sign bit 0, w < 0x8000
    u32 pos = atomicAdd(&cur[cl], 1u);
    csr[pos] = (r << 15) | (u32)w;
  }
}

// ---------------- layer-1 scalar propagate: s = Ahat * x --------------------
// 16-lane group per node, lanes split edges.
__global__ __launch_bounds__(256) void sprop_kernel(
    const u32* __restrict__ csr, const int* __restrict__ offs,
    const u16* __restrict__ zx, const float* __restrict__ dinv,
    float* __restrict__ sbuf) {
  int t = blockIdx.x * 256 + threadIdx.x;
  int n = t >> 4, sub = t & 15;
  float a = 0.f;
  int s = offs[n], e = offs[n + 1];
  for (int i = s + sub; i < e; i += 16) {
    u32 ee = __builtin_nontemporal_load(&csr[i]);
    a += bf2f(ee & 0x7FFFu) * bf2f((u32)zx[ee >> 15]);
  }
#pragma unroll
  for (int o = 8; o; o >>= 1) a += __shfl_xor(a, o, 64);
  if (sub == 0) sbuf[n] = dinv[n] * a;
}

// ---------------- layer-1 epilogue + transform -> [N][FDIM] bf16 ------------
// out1 = relu(s*w1i + x*w1r + b1); store (out1 @ w1) * dinv as bf16.
__global__ __launch_bounds__(256) void conv1_mid_kernel(
    const float* __restrict__ sbuf, const float* __restrict__ x,
    const float* __restrict__ dinv,
    const float* __restrict__ w1i, const float* __restrict__ w1r,
    const float* __restrict__ b1, const float* __restrict__ w1,
    u16* __restrict__ tout) {
  int t = blockIdx.x * 256 + threadIdx.x;
  int n = t >> 4, c = t & 15;
  int base = (threadIdx.x & 63) & 48;
  float sn = sbuf[n], xn = x[n], dn = dinv[n];
#pragma unroll
  for (int k = 0; k < 3; ++k) {
    float u = fmaxf(sn * w1i[k * 16 + c] + xn * w1r[k * 16 + c] + b1[k * 16 + c], 0.f);
    float tf = 0.f;
#pragma unroll
    for (int f = 0; f < 16; ++f) tf += __shfl(u, base + f, 64) * w1[k * 256 + f * 16 + c];
    tout[(size_t)n * FDIM + k * 16 + c] = f2bf(tf * dn);
  }
}

// ---------------- conv1 propagate, all 3 stacks combined --------------------
// wave per node, lane = channel, 48 active; rows 128 B line-aligned.
// R10-measured loop: UNMASKED unroll-8 with EXPLICIT SCALARS (no indexed
// locals -> no scratch demotion), then unroll-4, scalar tail. nt CSR loads.
__global__ __launch_bounds__(256) void conv1_prop_kernel(
    const u16* __restrict__ tin, u16* __restrict__ tout, float* __restrict__ hbuf,
    const u32* __restrict__ csr, const int* __restrict__ offs,
    const float* __restrict__ dinv, const float* __restrict__ x,
    const float* __restrict__ w1r, const float* __restrict__ b1,
    const float* __restrict__ w1, int do_t) {
  int lane = threadIdx.x & 63;
  int wid = (blockIdx.x * blockDim.x + threadIdx.x) >> 6;
  int nw = (gridDim.x * blockDim.x) >> 6;
  int c = lane;
  bool act = c < KH;
  float rb = act ? w1r[c] : 0.f;
  float bb = act ? b1[c] : 0.f;
  float wreg[16];
  if (do_t) {
    int k = c >> 4, o = c & 15;
    if (act) {
#pragma unroll
      for (int f = 0; f < 16; ++f) wreg[f] = w1[k * 256 + f * 16 + o];
    } else {
#pragma unroll
      for (int f = 0; f < 16; ++f) wreg[f] = 0.f;
    }
  }
  for (int n = wid; n < N_NODES; n += nw) {
    int nu = __builtin_amdgcn_readfirstlane(n);
    int s = offs[nu], e = offs[nu + 1];
    float acc = 0.f;
    int i = s;
    for (; i + 8 <= e; i += 8) {
      u32 e0 = __builtin_nontemporal_load(&csr[i]);
      u32 e1 = __builtin_nontemporal_load(&csr[i + 1]);
      u32 e2 = __builtin_nontemporal_load(&csr[i + 2]);
      u32 e3 = __builtin_nontemporal_load(&csr[i + 3]);
      u32 e4 = __builtin_nontemporal_load(&csr[i + 4]);
      u32 e5 = __builtin_nontemporal_load(&csr[i + 5]);
      u32 e6 = __builtin_nontemporal_load(&csr[i + 6]);
      u32 e7 = __builtin_nontemporal_load(&csr[i + 7]);
      float v0 = 0.f, v1 = 0.f, v2 = 0.f, v3 = 0.f;
      float v4 = 0.f, v5 = 0.f, v6 = 0.f, v7 = 0.f;
      if (act) {
        v0 = bf2f((u32)tin[(e0 >> 15) * FDIM + c]);
        v1 = bf2f((u32)tin[(e1 >> 15) * FDIM + c]);
        v2 = bf2f((u32)tin[(e2 >> 15) * FDIM + c]);
        v3 = bf2f((u32)tin[(e3 >> 15) * FDIM + c]);
        v4 = bf2f((u32)tin[(e4 >> 15) * FDIM + c]);
        v5 = bf2f((u32)tin[(e5 >> 15) * FDIM + c]);
        v6 = bf2f((u32)tin[(e6 >> 15) * FDIM + c]);
        v7 = bf2f((u32)tin[(e7 >> 15) * FDIM + c]);
      }
      acc += bf2f(e0 & 0x7FFFu) * v0 + bf2f(e1 & 0x7FFFu) * v1 +
             bf2f(e2 & 0x7FFFu) * v2 + bf2f(e3 & 0x7FFFu) * v3 +
             bf2f(e4 & 0x7FFFu) * v4 + bf2f(e5 & 0x7FFFu) * v5 +
             bf2f(e6 & 0x7FFFu) * v6 + bf2f(e7 & 0x7FFFu) * v7;
    }
    for (; i + 4 <= e; i += 4) {
      u32 e0 = __builtin_nontemporal_load(&csr[i]);
      u32 e1 = __builtin_nontemporal_load(&csr[i + 1]);
      u32 e2 = __builtin_nontemporal_load(&csr[i + 2]);
      u32 e3 = __builtin_nontemporal_load(&csr[i + 3]);
      float v0 = 0.f, v1 = 0.f, v2 = 0.f, v3 = 0.f;
      if (act) {
        v0 = bf2f((u32)tin[(e0 >> 15) * FDIM + c]);
        v1 = bf2f((u32)tin[(e1 >> 15) * FDIM + c]);
        v2 = bf2f((u32)tin[(e2 >> 15) * FDIM + c]);
        v3 = bf2f((u32)tin[(e3 >> 15) * FDIM + c]);
      }
      acc += bf2f(e0 & 0x7FFFu) * v0 + bf2f(e1 & 0x7FFFu) * v1 +
             bf2f(e2 & 0x7FFFu) * v2 + bf2f(e3 & 0x7FFFu) * v3;
    }
    for (; i < e; ++i) {
      u32 ee = __builtin_nontemporal_load(&csr[i]);
      if (act) acc += bf2f(ee & 0x7FFFu) * bf2f((u32)tin[(ee >> 15) * FDIM + c]);
    }
    float dn = dinv[nu];
    float u = fmaxf(acc * dn + x[nu] * rb + bb, 0.f);
    if (do_t) {
      float tf = 0.f;
      int base = c & 48;
#pragma unroll
      for (int f = 0; f < 16; ++f) tf += __shfl(u, base + f, 64) * wreg[f];
      if (act) tout[(size_t)nu * FDIM + c] = f2bf(tf * dn);
    } else {
      float m1v = __shfl(u, lane + 16, 64);
      float m2v = __shfl(u, lane + 32, 64);
      if (lane < NH) hbuf[(size_t)nu * NH + lane] = (u + m1v + m2v) * (1.f / 3.f);
    }
  }
}

// ---------------- BN stats over hbuf [N,16] ---------------------------------
__global__ __launch_bounds__(256) void bn_stats_kernel(
    const float* __restrict__ h, double* __restrict__ stats) {
  __shared__ float ssum[NH], ssq[NH];
  int tid = threadIdx.x;
  if (tid < NH) { ssum[tid] = 0.f; ssq[tid] = 0.f; }
  __syncthreads();
  int n = blockIdx.x * blockDim.x + tid;
  bool valid = n < N_NODES;
  const float4* p = (const float4*)(h + (size_t)(valid ? n : 0) * NH);
  float hv[NH];
#pragma unroll
  for (int q = 0; q < 4; ++q) {
    float4 v = valid ? p[q] : make_float4(0.f, 0.f, 0.f, 0.f);
    hv[q * 4 + 0] = v.x; hv[q * 4 + 1] = v.y; hv[q * 4 + 2] = v.z; hv[q * 4 + 3] = v.w;
  }
#pragma unroll
  for (int f = 0; f < NH; ++f) {
    float s = hv[f], q = hv[f] * hv[f];
    for (int o = 32; o; o >>= 1) { s += __shfl_xor(s, o, 64); q += __shfl_xor(q, o, 64); }
    if ((tid & 63) == 0) { atomicAdd(&ssum[f], s); atomicAdd(&ssq[f], q); }
  }
  __syncthreads();
  if (tid < NH) {
    atomicAdd(&stats[tid], (double)ssum[tid]);
    atomicAdd(&stats[NH + tid], (double)ssq[tid]);
  }
}

__global__ __launch_bounds__(64) void bn_final_kernel(
    const double* __restrict__ stats, const float* __restrict__ g,
    const float* __restrict__ b, float* __restrict__ sc, float* __restrict__ sh) {
  int f = threadIdx.x;
  if (f < NH) {
    double mu = stats[f] / (double)N_NODES;
    double var = stats[NH + f] / (double)N_NODES - mu * mu;
    float scale = g[f] * (float)(1.0 / sqrt(var + (double)BN_EPS));
    sc[f] = scale;
    sh[f] = b[f] - (float)mu * scale;
  }
}

// ---------------- conv2 init: BN-apply + relu + init/root dots --------------
__global__ __launch_bounds__(256) void conv2_init_kernel(
    const float* __restrict__ h, const float* __restrict__ sc, const float* __restrict__ sh,
    const float* __restrict__ dinv,
    const float* __restrict__ w2i, const float* __restrict__ w2r, const float* __restrict__ b2,
    float* __restrict__ P, float* __restrict__ R) {
  int n = blockIdx.x * blockDim.x + threadIdx.x;
  if (n >= N_NODES) return;
  float u[NH];
#pragma unroll
  for (int f = 0; f < NH; ++f) u[f] = fmaxf(h[(size_t)n * NH + f] * sc[f] + sh[f], 0.f);
  float dn = dinv[n];
#pragma unroll
  for (int k = 0; k < 3; ++k) {
    float r = b2[k], o = 0.f;
#pragma unroll
    for (int f = 0; f < NH; ++f) {
      r += u[f] * w2r[k * NH + f];
      o += u[f] * w2i[k * NH + f];
    }
    R[n * 4 + k] = r;
    P[n * 4 + k] = o * dn;
  }
  R[n * 4 + 3] = 0.f;
  P[n * 4 + 3] = 0.f;
}

// ---------------- conv2 propagate: 16-lane groups, packed CSR ---------------
__global__ __launch_bounds__(256) void conv2_prop_kernel(
    const float* __restrict__ in4, float* __restrict__ out4, float* __restrict__ y,
    const u32* __restrict__ csr, const int* __restrict__ offs,
    const float* __restrict__ dinv,
    const float* __restrict__ R, const float* __restrict__ w2,
    int scale_w2, int final_out) {
  int t = blockIdx.x * 256 + threadIdx.x;
  int n = t >> 4, sub = t & 15;
  float m0 = 1.f, m1 = 1.f, m2 = 1.f;
  if (scale_w2) { m0 = w2[0]; m1 = w2[1]; m2 = w2[2]; }
  int s = offs[n], e = offs[n + 1];
  float a0 = 0.f, a1 = 0.f, a2 = 0.f;
  for (int i = s + sub; i < e; i += 16) {
    u32 ee = __builtin_nontemporal_load(&csr[i]);
    float w = bf2f(ee & 0x7FFFu);
    const float4 v = *(const float4*)(in4 + (size_t)(ee >> 15) * 4);
    a0 += w * v.x;
    a1 += w * v.y;
    a2 += w * v.z;
  }
#pragma unroll
  for (int o = 8; o; o >>= 1) {
    a0 += __shfl_xor(a0, o, 64);
    a1 += __shfl_xor(a1, o, 64);
    a2 += __shfl_xor(a2, o, 64);
  }
  if (sub == 0) {
    float dn = dinv[n];
    a0 = a0 * dn * m0 + R[n * 4 + 0];
    a1 = a1 * dn * m1 + R[n * 4 + 1];
    a2 = a2 * dn * m2 + R[n * 4 + 2];
    if (final_out) {
      float sm = (a0 + a1 + a2) * (1.f / 3.f);
      y[n] = 1.f / (1.f + expf(-sm));
    } else {
      out4[n * 4 + 0] = a0 * dn;
      out4[n * 4 + 1] = a1 * dn;
      out4[n * 4 + 2] = a2 * dn;
      out4[n * 4 + 3] = 0.f;
    }
  }
}

extern "C" void kernel_launch(void* const* d_in, const int* in_sizes, int n_in,
                              void* d_out, int out_size, void* d_ws, size_t ws_size,
                              hipStream_t stream) {
  const float* x   = (const float*)d_in[0];
  const int*   ei  = (const int*)d_in[1];
  const float* ea  = (const float*)d_in[2];
  // d_in[3] = batch (unused)
  const float* w1i = (const float*)d_in[4];
  const float* w1  = (const float*)d_in[5];
  const float* w1r = (const float*)d_in[6];
  const float* b1  = (const float*)d_in[7];
  const float* bng = (const float*)d_in[8];
  const float* bnb = (const float*)d_in[9];
  const float* w2i = (const float*)d_in[10];
  const float* w2  = (const float*)d_in[11];
  const float* w2r = (const float*)d_in[12];
  const float* b2  = (const float*)d_in[13];
  float* y = (float*)d_out;

  const int* row = ei;
  const int* col = ei + N_EDGES;

  char* ws = (char*)d_ws;
  size_t off = 0;
  auto alloc = [&](size_t bytes) -> char* {
    char* p = ws + off;
    off += (bytes + 255) & ~(size_t)255;
    return p;
  };
  u32*    btot   = (u32*)alloc((size_t)NBUCK * 8 * 4);
  u32*    gcur   = (u32*)alloc((size_t)NBUCK * 8 * 4);
  u32*    bstart = (u32*)alloc((size_t)(NBUCK + 1) * 4);
  int*    offs   = (int*)alloc((size_t)(N_NODES + 1) * 4);
  float*  dinv   = (float*)alloc((size_t)N_NODES * 4);
  u16*    zx     = (u16*)alloc((size_t)N_NODES * 2);
  float*  sbuf   = (float*)alloc((size_t)N_NODES * 4);
  double* stats  = (double*)alloc(32 * 8);
  float*  bnsc   = (float*)alloc(16 * 4);
  float*  bnsh   = (float*)alloc(16 * 4);
  int2*   bucketed = (int2*)alloc((size_t)N_EDGES * 8);
  u32*    csr    = (u32*)alloc((size_t)N_EDGES * 4);
  u16*    tA     = (u16*)alloc((size_t)N_NODES * FDIM * 2);
  u16*    tB     = (u16*)alloc((size_t)N_NODES * FDIM * 2);
  float*  hbuf   = (float*)alloc((size_t)N_NODES * NH * 4);
  float*  P2     = (float*)alloc((size_t)N_NODES * 4 * 4);
  float*  Q2     = (float*)alloc((size_t)N_NODES * 4 * 4);
  float*  R2     = (float*)alloc((size_t)N_NODES * 4 * 4);
  (void)ws_size; (void)in_sizes; (void)n_in; (void)out_size;

  hipMemsetAsync(btot, 0, (size_t)NBUCK * 8 * 4, stream);
  hipMemsetAsync(stats, 0, 32 * 8, stream);

  bucket_count_kernel<<<NBLK1, 256, 0, stream>>>(col, btot);
  bucket_scan_kernel<<<1, 256, 0, stream>>>(btot, bstart, gcur, offs);
  bucket_scatter_kernel<<<NBLK1, 256, 0, stream>>>(row, col, ea, gcur, bucketed);
  node_offs_kernel<<<NBUCK, 1024, 0, stream>>>(bucketed, bstart, x, offs, dinv, zx);
  csr_fill_kernel<<<NBUCK, 1024, 0, stream>>>(bucketed, bstart, offs, csr);

  const int NPB = 6250;  // N_NODES*16/256 exactly
  // conv1 layer 1 (rank-1 collapse): scalar prop + dense epilogue -> tA
  sprop_kernel<<<NPB, 256, 0, stream>>>(csr, offs, zx, dinv, sbuf);
  conv1_mid_kernel<<<NPB, 256, 0, stream>>>(sbuf, x, dinv, w1i, w1r, b1, w1, tA);
  // conv1 layers 2-4: combined 3-stack propagation (R10-proven loop, grid 4096)
  conv1_prop_kernel<<<4096, 256, 0, stream>>>(tA, tB, nullptr, csr, offs, dinv, x, w1r, b1, w1, 1);
  conv1_prop_kernel<<<4096, 256, 0, stream>>>(tB, tA, nullptr, csr, offs, dinv, x, w1r, b1, w1, 1);
  conv1_prop_kernel<<<4096, 256, 0, stream>>>(tA, nullptr, hbuf, csr, offs, dinv, x, w1r, b1, w1, 0);

  bn_stats_kernel<<<(N_NODES + 255) / 256, 256, 0, stream>>>(hbuf, stats);
  bn_final_kernel<<<1, 64, 0, stream>>>(stats, bng, bnb, bnsc, bnsh);
  conv2_init_kernel<<<(N_NODES + 255) / 256, 256, 0, stream>>>(
      hbuf, bnsc, bnsh, dinv, w2i, w2r, b2, P2, R2);

  conv2_prop_kernel<<<NPB, 256, 0, stream>>>(P2, Q2, nullptr, csr, offs, dinv, R2, w2, 0, 0);
  conv2_prop_kernel<<<NPB, 256, 0, stream>>>(Q2, P2, nullptr, csr, offs, dinv, R2, w2, 1, 0);
  conv2_prop_kernel<<<NPB, 256, 0, stream>>>(P2, Q2, nullptr, csr, offs, dinv, R2, w2, 1, 0);
  conv2_prop_kernel<<<NPB, 256, 0, stream>>>(Q2, P2, y, csr, offs, dinv, R2, w2, 1, 1);
}

// Round 13
// 522.059 us; speedup vs baseline: 1.6577x; 1.0531x over previous
//
#include <hip/hip_runtime.h>
#include <math.h>

#define N_NODES 100000
#define N_EDGES 3200000
#define KH 48            // K*H active channels
#define FDIM 64          // padded feature row stride (128 B, line-aligned)
#define NH 16            // H
#define BN_EPS 1e-5f
#define NBUCK 196        // ceil(100000/512) buckets of 512 nodes
#define BSHIFT 9
#define BMASK 511
#define EPB 16384        // edges per block in bucket kernels
#define NBLK1 196        // ceil(N_EDGES/EPB)
#define FIX 16777216.0f  // 2^24 fixed point for degree sums

typedef unsigned long long u64;
typedef unsigned int u32;
typedef unsigned short u16;

__device__ __forceinline__ u16 f2bf(float f) {
  u32 b = __float_as_uint(f);
  b += 0x7FFFu + ((b >> 16) & 1u);   // RNE
  return (u16)(b >> 16);
}
__device__ __forceinline__ float bf2f(u32 s) {
  return __uint_as_float(s << 16);
}

// ---------------- K1: per-block LDS bucket histogram -> global totals -------
__global__ __launch_bounds__(256) void bucket_count_kernel(
    const int* __restrict__ col, u32* __restrict__ btot /* stride 8 */) {
  __shared__ u32 bins[NBUCK];
  for (int t = threadIdx.x; t < NBUCK; t += 256) bins[t] = 0;
  __syncthreads();
  int eb = blockIdx.x * EPB;
  for (int it = 0; it < EPB / 256; ++it) {
    int e = eb + it * 256 + threadIdx.x;
    if (e < N_EDGES) atomicAdd(&bins[col[e] >> BSHIFT], 1u);
  }
  __syncthreads();
  for (int t = threadIdx.x; t < NBUCK; t += 256)
    if (bins[t]) atomicAdd(&btot[t * 8], bins[t]);
}

// ---------------- K2: scan bucket totals -> starts, init cursors ------------
__global__ __launch_bounds__(256) void bucket_scan_kernel(
    const u32* __restrict__ btot, u32* __restrict__ bstart, u32* __restrict__ gcur,
    int* __restrict__ offs) {
  __shared__ u32 sh[256];
  int t = threadIdx.x;
  u32 v = (t < NBUCK) ? btot[t * 8] : 0;
  sh[t] = v;
  __syncthreads();
  for (int d = 1; d < 256; d <<= 1) {
    u32 u = (t >= d) ? sh[t - d] : 0;
    __syncthreads();
    sh[t] += u;
    __syncthreads();
  }
  if (t < NBUCK) { u32 s = sh[t] - v; bstart[t] = s; gcur[t * 8] = s; }
  if (t == NBUCK) bstart[NBUCK] = N_EDGES;
  if (t == 0) offs[N_NODES] = N_EDGES;
}

// ---------------- K3: scatter edges into bucket-major order -----------------
__global__ __launch_bounds__(256) void bucket_scatter_kernel(
    const int* __restrict__ row, const int* __restrict__ col,
    const float* __restrict__ ea, u32* __restrict__ gcur,
    int2* __restrict__ bucketed) {
  __shared__ u32 bins[NBUCK];
  __shared__ u32 base[NBUCK];
  __shared__ u16 rnk[EPB];
  for (int t = threadIdx.x; t < NBUCK; t += 256) bins[t] = 0;
  __syncthreads();
  int eb = blockIdx.x * EPB;
  for (int it = 0; it < EPB / 256; ++it) {
    int i = it * 256 + threadIdx.x;
    int e = eb + i;
    if (e < N_EDGES) rnk[i] = (u16)atomicAdd(&bins[col[e] >> BSHIFT], 1u);
  }
  __syncthreads();
  for (int t = threadIdx.x; t < NBUCK; t += 256) {
    u32 c = bins[t];
    if (c) base[t] = atomicAdd(&gcur[t * 8], c);
  }
  __syncthreads();
  for (int it = 0; it < EPB / 256; ++it) {
    int i = it * 256 + threadIdx.x;
    int e = eb + i;
    if (e < N_EDGES) {
      int c = col[e];
      int bkt = c >> BSHIFT, cl = c & BMASK;
      u32 pos = base[bkt] + (u32)rnk[i];
      bucketed[pos] = make_int2((cl << 17) | row[e], __float_as_int(ea[e]));
    }
  }
}

// ---------------- P2a: per-bucket node counts -> offs, dinv, zx -------------
__global__ __launch_bounds__(1024) void node_offs_kernel(
    const int2* __restrict__ bucketed, const u32* __restrict__ bstart,
    const float* __restrict__ x,
    int* __restrict__ offs, float* __restrict__ dinv, u16* __restrict__ zx) {
  __shared__ u32 cnt[512];
  __shared__ u32 degf[512];
  int t = threadIdx.x;
  if (t < 512) { cnt[t] = 0; degf[t] = 0; }
  __syncthreads();
  int b = blockIdx.x;
  u32 s = bstart[b], e = bstart[b + 1];
  for (u32 i = s + t; i < e; i += 1024) {
    int2 v = bucketed[i];
    int cl = (v.x >> 17) & BMASK;
    atomicAdd(&cnt[cl], 1u);
    atomicAdd(&degf[cl], (u32)(__int_as_float(v.y) * FIX));
  }
  __syncthreads();
  u32 v0 = (t < 512) ? cnt[t] : 0;
  for (int d = 1; d < 512; d <<= 1) {
    u32 u = (t < 512 && t >= d) ? cnt[t - d] : 0;
    __syncthreads();
    if (t < 512) cnt[t] += u;
    __syncthreads();
  }
  int n = b * 512 + t;
  if (t < 512 && n < N_NODES) {
    offs[n] = (int)(s + cnt[t] - v0);  // exclusive
    float dg = (float)degf[t] * (1.0f / FIX);
    float dv = dg > 0.f ? rsqrtf(fmaxf(dg, 1e-12f)) : 0.f;
    dinv[n] = dv;
    zx[n] = f2bf(x[n] * dv);
  }
}

// ---------------- P2b: packed 4B CSR: (src<<15) | bf16(ea) ------------------
__global__ __launch_bounds__(1024) void csr_fill_kernel(
    const int2* __restrict__ bucketed, const u32* __restrict__ bstart,
    const int* __restrict__ offs, u32* __restrict__ csr) {
  __shared__ u32 cur[512];
  int t = threadIdx.x;
  int b = blockIdx.x;
  int n = b * 512 + t;
  if (t < 512) cur[t] = (n < N_NODES) ? (u32)offs[n] : 0;
  __syncthreads();
  u32 s = bstart[b], e = bstart[b + 1];
  for (u32 i = s + t; i < e; i += 1024) {
    int2 v = bucketed[i];
    int cl = (v.x >> 17) & BMASK;
    u32 r = (u32)(v.x & 0x1FFFF);
    u16 w = f2bf(__int_as_float(v.y));   // ea >= 0 -> sign bit 0, w < 0x8000
    u32 pos = atomicAdd(&cur[cl], 1u);
    csr[pos] = (r << 15) | (u32)w;
  }
}

// ---------------- layer-1: scalar prop + epilogue + transform (merged) ------
// 16-lane group per node. Lanes split edges for s = Ahat*x (butterfly gives
// all lanes the sum), then lane c does the dense epilogue for channel c.
__global__ __launch_bounds__(256) void sprop_mid_kernel(
    const u32* __restrict__ csr, const int* __restrict__ offs,
    const u16* __restrict__ zx, const float* __restrict__ dinv,
    const float* __restrict__ x,
    const float* __restrict__ w1i, const float* __restrict__ w1r,
    const float* __restrict__ b1, const float* __restrict__ w1,
    u16* __restrict__ tout) {
  int t = blockIdx.x * 256 + threadIdx.x;
  int n = t >> 4, c = t & 15;
  float a = 0.f;
  int s = offs[n], e = offs[n + 1];
  for (int i = s + c; i < e; i += 16) {
    u32 ee = csr[i];
    a += bf2f(ee & 0x7FFFu) * bf2f((u32)zx[ee >> 15]);
  }
#pragma unroll
  for (int o = 8; o; o >>= 1) a += __shfl_xor(a, o, 64);
  float dn = dinv[n];
  float sn = a * dn;
  float xn = x[n];
  int base = (threadIdx.x & 63) & 48;
#pragma unroll
  for (int k = 0; k < 3; ++k) {
    float u = fmaxf(sn * w1i[k * 16 + c] + xn * w1r[k * 16 + c] + b1[k * 16 + c], 0.f);
    float tf = 0.f;
#pragma unroll
    for (int f = 0; f < 16; ++f) tf += __shfl(u, base + f, 64) * w1[k * 256 + f * 16 + c];
    tout[(size_t)n * FDIM + k * 16 + c] = f2bf(tf * dn);
  }
}

// ---------------- conv1 propagate, all 3 stacks combined --------------------
// wave per node, lane = channel, 48 active; rows 128 B line-aligned.
// R10-measured loop: UNMASKED unroll-8 with EXPLICIT SCALARS (no indexed
// locals -> no scratch demotion), then unroll-4, scalar tail. nt CSR loads.
__global__ __launch_bounds__(256) void conv1_prop_kernel(
    const u16* __restrict__ tin, u16* __restrict__ tout, float* __restrict__ hbuf,
    const u32* __restrict__ csr, const int* __restrict__ offs,
    const float* __restrict__ dinv, const float* __restrict__ x,
    const float* __restrict__ w1r, const float* __restrict__ b1,
    const float* __restrict__ w1, int do_t) {
  int lane = threadIdx.x & 63;
  int wid = (blockIdx.x * blockDim.x + threadIdx.x) >> 6;
  int nw = (gridDim.x * blockDim.x) >> 6;
  int c = lane;
  bool act = c < KH;
  float rb = act ? w1r[c] : 0.f;
  float bb = act ? b1[c] : 0.f;
  float wreg[16];
  if (do_t) {
    int k = c >> 4, o = c & 15;
    if (act) {
#pragma unroll
      for (int f = 0; f < 16; ++f) wreg[f] = w1[k * 256 + f * 16 + o];
    } else {
#pragma unroll
      for (int f = 0; f < 16; ++f) wreg[f] = 0.f;
    }
  }
  for (int n = wid; n < N_NODES; n += nw) {
    int nu = __builtin_amdgcn_readfirstlane(n);
    int s = offs[nu], e = offs[nu + 1];
    float acc = 0.f;
    int i = s;
    for (; i + 8 <= e; i += 8) {
      u32 e0 = __builtin_nontemporal_load(&csr[i]);
      u32 e1 = __builtin_nontemporal_load(&csr[i + 1]);
      u32 e2 = __builtin_nontemporal_load(&csr[i + 2]);
      u32 e3 = __builtin_nontemporal_load(&csr[i + 3]);
      u32 e4 = __builtin_nontemporal_load(&csr[i + 4]);
      u32 e5 = __builtin_nontemporal_load(&csr[i + 5]);
      u32 e6 = __builtin_nontemporal_load(&csr[i + 6]);
      u32 e7 = __builtin_nontemporal_load(&csr[i + 7]);
      float v0 = 0.f, v1 = 0.f, v2 = 0.f, v3 = 0.f;
      float v4 = 0.f, v5 = 0.f, v6 = 0.f, v7 = 0.f;
      if (act) {
        v0 = bf2f((u32)tin[(e0 >> 15) * FDIM + c]);
        v1 = bf2f((u32)tin[(e1 >> 15) * FDIM + c]);
        v2 = bf2f((u32)tin[(e2 >> 15) * FDIM + c]);
        v3 = bf2f((u32)tin[(e3 >> 15) * FDIM + c]);
        v4 = bf2f((u32)tin[(e4 >> 15) * FDIM + c]);
        v5 = bf2f((u32)tin[(e5 >> 15) * FDIM + c]);
        v6 = bf2f((u32)tin[(e6 >> 15) * FDIM + c]);
        v7 = bf2f((u32)tin[(e7 >> 15) * FDIM + c]);
      }
      acc += bf2f(e0 & 0x7FFFu) * v0 + bf2f(e1 & 0x7FFFu) * v1 +
             bf2f(e2 & 0x7FFFu) * v2 + bf2f(e3 & 0x7FFFu) * v3 +
             bf2f(e4 & 0x7FFFu) * v4 + bf2f(e5 & 0x7FFFu) * v5 +
             bf2f(e6 & 0x7FFFu) * v6 + bf2f(e7 & 0x7FFFu) * v7;
    }
    for (; i + 4 <= e; i += 4) {
      u32 e0 = __builtin_nontemporal_load(&csr[i]);
      u32 e1 = __builtin_nontemporal_load(&csr[i + 1]);
      u32 e2 = __builtin_nontemporal_load(&csr[i + 2]);
      u32 e3 = __builtin_nontemporal_load(&csr[i + 3]);
      float v0 = 0.f, v1 = 0.f, v2 = 0.f, v3 = 0.f;
      if (act) {
        v0 = bf2f((u32)tin[(e0 >> 15) * FDIM + c]);
        v1 = bf2f((u32)tin[(e1 >> 15) * FDIM + c]);
        v2 = bf2f((u32)tin[(e2 >> 15) * FDIM + c]);
        v3 = bf2f((u32)tin[(e3 >> 15) * FDIM + c]);
      }
      acc += bf2f(e0 & 0x7FFFu) * v0 + bf2f(e1 & 0x7FFFu) * v1 +
             bf2f(e2 & 0x7FFFu) * v2 + bf2f(e3 & 0x7FFFu) * v3;
    }
    for (; i < e; ++i) {
      u32 ee = __builtin_nontemporal_load(&csr[i]);
      if (act) acc += bf2f(ee & 0x7FFFu) * bf2f((u32)tin[(ee >> 15) * FDIM + c]);
    }
    float dn = dinv[nu];
    float u = fmaxf(acc * dn + x[nu] * rb + bb, 0.f);
    if (do_t) {
      float tf = 0.f;
      int base = c & 48;
#pragma unroll
      for (int f = 0; f < 16; ++f) tf += __shfl(u, base + f, 64) * wreg[f];
      if (act) tout[(size_t)nu * FDIM + c] = f2bf(tf * dn);
    } else {
      float m1v = __shfl(u, lane + 16, 64);
      float m2v = __shfl(u, lane + 32, 64);
      if (lane < NH) hbuf[(size_t)nu * NH + lane] = (u + m1v + m2v) * (1.f / 3.f);
    }
  }
}

// ---------------- BN stats over hbuf [N,16] ---------------------------------
__global__ __launch_bounds__(256) void bn_stats_kernel(
    const float* __restrict__ h, double* __restrict__ stats) {
  __shared__ float ssum[NH], ssq[NH];
  int tid = threadIdx.x;
  if (tid < NH) { ssum[tid] = 0.f; ssq[tid] = 0.f; }
  __syncthreads();
  int n = blockIdx.x * blockDim.x + tid;
  bool valid = n < N_NODES;
  const float4* p = (const float4*)(h + (size_t)(valid ? n : 0) * NH);
  float hv[NH];
#pragma unroll
  for (int q = 0; q < 4; ++q) {
    float4 v = valid ? p[q] : make_float4(0.f, 0.f, 0.f, 0.f);
    hv[q * 4 + 0] = v.x; hv[q * 4 + 1] = v.y; hv[q * 4 + 2] = v.z; hv[q * 4 + 3] = v.w;
  }
#pragma unroll
  for (int f = 0; f < NH; ++f) {
    float s = hv[f], q = hv[f] * hv[f];
    for (int o = 32; o; o >>= 1) { s += __shfl_xor(s, o, 64); q += __shfl_xor(q, o, 64); }
    if ((tid & 63) == 0) { atomicAdd(&ssum[f], s); atomicAdd(&ssq[f], q); }
  }
  __syncthreads();
  if (tid < NH) {
    atomicAdd(&stats[tid], (double)ssum[tid]);
    atomicAdd(&stats[NH + tid], (double)ssq[tid]);
  }
}

__global__ __launch_bounds__(64) void bn_final_kernel(
    const double* __restrict__ stats, const float* __restrict__ g,
    const float* __restrict__ b, float* __restrict__ sc, float* __restrict__ sh) {
  int f = threadIdx.x;
  if (f < NH) {
    double mu = stats[f] / (double)N_NODES;
    double var = stats[NH + f] / (double)N_NODES - mu * mu;
    float scale = g[f] * (float)(1.0 / sqrt(var + (double)BN_EPS));
    sc[f] = scale;
    sh[f] = b[f] - (float)mu * scale;
  }
}

// ---------------- conv2 init: BN-apply + relu + init/root dots --------------
__global__ __launch_bounds__(256) void conv2_init_kernel(
    const float* __restrict__ h, const float* __restrict__ sc, const float* __restrict__ sh,
    const float* __restrict__ dinv,
    const float* __restrict__ w2i, const float* __restrict__ w2r, const float* __restrict__ b2,
    float* __restrict__ P, float* __restrict__ R) {
  int n = blockIdx.x * blockDim.x + threadIdx.x;
  if (n >= N_NODES) return;
  float u[NH];
#pragma unroll
  for (int f = 0; f < NH; ++f) u[f] = fmaxf(h[(size_t)n * NH + f] * sc[f] + sh[f], 0.f);
  float dn = dinv[n];
#pragma unroll
  for (int k = 0; k < 3; ++k) {
    float r = b2[k], o = 0.f;
#pragma unroll
    for (int f = 0; f < NH; ++f) {
      r += u[f] * w2r[k * NH + f];
      o += u[f] * w2i[k * NH + f];
    }
    R[n * 4 + k] = r;
    P[n * 4 + k] = o * dn;
  }
  R[n * 4 + 3] = 0.f;
  P[n * 4 + 3] = 0.f;
}

// ---------------- conv2 propagate: 16-lane groups, packed CSR ---------------
// Plain (cached) CSR loads: per-XCD CSR slice (~1.6 MB) stays L2-resident
// across the 4 sequential passes.
__global__ __launch_bounds__(256) void conv2_prop_kernel(
    const float* __restrict__ in4, float* __restrict__ out4, float* __restrict__ y,
    const u32* __restrict__ csr, const int* __restrict__ offs,
    const float* __restrict__ dinv,
    const float* __restrict__ R, const float* __restrict__ w2,
    int scale_w2, int final_out) {
  int t = blockIdx.x * 256 + threadIdx.x;
  int n = t >> 4, sub = t & 15;
  float m0 = 1.f, m1 = 1.f, m2 = 1.f;
  if (scale_w2) { m0 = w2[0]; m1 = w2[1]; m2 = w2[2]; }
  int s = offs[n], e = offs[n + 1];
  float a0 = 0.f, a1 = 0.f, a2 = 0.f;
  for (int i = s + sub; i < e; i += 16) {
    u32 ee = csr[i];
    float w = bf2f(ee & 0x7FFFu);
    const float4 v = *(const float4*)(in4 + (size_t)(ee >> 15) * 4);
    a0 += w * v.x;
    a1 += w * v.y;
    a2 += w * v.z;
  }
#pragma unroll
  for (int o = 8; o; o >>= 1) {
    a0 += __shfl_xor(a0, o, 64);
    a1 += __shfl_xor(a1, o, 64);
    a2 += __shfl_xor(a2, o, 64);
  }
  if (sub == 0) {
    float dn = dinv[n];
    a0 = a0 * dn * m0 + R[n * 4 + 0];
    a1 = a1 * dn * m1 + R[n * 4 + 1];
    a2 = a2 * dn * m2 + R[n * 4 + 2];
    if (final_out) {
      float sm = (a0 + a1 + a2) * (1.f / 3.f);
      y[n] = 1.f / (1.f + expf(-sm));
    } else {
      out4[n * 4 + 0] = a0 * dn;
      out4[n * 4 + 1] = a1 * dn;
      out4[n * 4 + 2] = a2 * dn;
      out4[n * 4 + 3] = 0.f;
    }
  }
}

extern "C" void kernel_launch(void* const* d_in, const int* in_sizes, int n_in,
                              void* d_out, int out_size, void* d_ws, size_t ws_size,
                              hipStream_t stream) {
  const float* x   = (const float*)d_in[0];
  const int*   ei  = (const int*)d_in[1];
  const float* ea  = (const float*)d_in[2];
  // d_in[3] = batch (unused)
  const float* w1i = (const float*)d_in[4];
  const float* w1  = (const float*)d_in[5];
  const float* w1r = (const float*)d_in[6];
  const float* b1  = (const float*)d_in[7];
  const float* bng = (const float*)d_in[8];
  const float* bnb = (const float*)d_in[9];
  const float* w2i = (const float*)d_in[10];
  const float* w2  = (const float*)d_in[11];
  const float* w2r = (const float*)d_in[12];
  const float* b2  = (const float*)d_in[13];
  float* y = (float*)d_out;

  const int* row = ei;
  const int* col = ei + N_EDGES;

  char* ws = (char*)d_ws;
  size_t off = 0;
  auto alloc = [&](size_t bytes) -> char* {
    char* p = ws + off;
    off += (bytes + 255) & ~(size_t)255;
    return p;
  };
  u32*    btot   = (u32*)alloc((size_t)NBUCK * 8 * 4);
  u32*    gcur   = (u32*)alloc((size_t)NBUCK * 8 * 4);
  u32*    bstart = (u32*)alloc((size_t)(NBUCK + 1) * 4);
  int*    offs   = (int*)alloc((size_t)(N_NODES + 1) * 4);
  float*  dinv   = (float*)alloc((size_t)N_NODES * 4);
  u16*    zx     = (u16*)alloc((size_t)N_NODES * 2);
  double* stats  = (double*)alloc(32 * 8);
  float*  bnsc   = (float*)alloc(16 * 4);
  float*  bnsh   = (float*)alloc(16 * 4);
  int2*   bucketed = (int2*)alloc((size_t)N_EDGES * 8);
  u32*    csr    = (u32*)alloc((size_t)N_EDGES * 4);
  u16*    tA     = (u16*)alloc((size_t)N_NODES * FDIM * 2);
  u16*    tB     = (u16*)alloc((size_t)N_NODES * FDIM * 2);
  float*  hbuf   = (float*)alloc((size_t)N_NODES * NH * 4);
  float*  P2     = (float*)alloc((size_t)N_NODES * 4 * 4);
  float*  Q2     = (float*)alloc((size_t)N_NODES * 4 * 4);
  float*  R2     = (float*)alloc((size_t)N_NODES * 4 * 4);
  (void)ws_size; (void)in_sizes; (void)n_in; (void)out_size;

  hipMemsetAsync(btot, 0, (size_t)NBUCK * 8 * 4, stream);
  hipMemsetAsync(stats, 0, 32 * 8, stream);

  bucket_count_kernel<<<NBLK1, 256, 0, stream>>>(col, btot);
  bucket_scan_kernel<<<1, 256, 0, stream>>>(btot, bstart, gcur, offs);
  bucket_scatter_kernel<<<NBLK1, 256, 0, stream>>>(row, col, ea, gcur, bucketed);
  node_offs_kernel<<<NBUCK, 1024, 0, stream>>>(bucketed, bstart, x, offs, dinv, zx);
  csr_fill_kernel<<<NBUCK, 1024, 0, stream>>>(bucketed, bstart, offs, csr);

  const int NPB = 6250;  // N_NODES*16/256 exactly
  // conv1 layer 1 (rank-1 collapse): merged scalar prop + dense epilogue -> tA
  sprop_mid_kernel<<<NPB, 256, 0, stream>>>(csr, offs, zx, dinv, x, w1i, w1r, b1, w1, tA);
  // conv1 layers 2-4: combined 3-stack propagation (R10-proven loop, grid 4096)
  conv1_prop_kernel<<<4096, 256, 0, stream>>>(tA, tB, nullptr, csr, offs, dinv, x, w1r, b1, w1, 1);
  conv1_prop_kernel<<<4096, 256, 0, stream>>>(tB, tA, nullptr, csr, offs, dinv, x, w1r, b1, w1, 1);
  conv1_prop_kernel<<<4096, 256, 0, stream>>>(tA, nullptr, hbuf, csr, offs, dinv, x, w1r, b1, w1, 0);

  bn_stats_kernel<<<(N_NODES + 255) / 256, 256, 0, stream>>>(hbuf, stats);
  bn_final_kernel<<<1, 64, 0, stream>>>(stats, bng, bnb, bnsc, bnsh);
  conv2_init_kernel<<<(N_NODES + 255) / 256, 256, 0, stream>>>(
      hbuf, bnsc, bnsh, dinv, w2i, w2r, b2, P2, R2);

  conv2_prop_kernel<<<NPB, 256, 0, stream>>>(P2, Q2, nullptr, csr, offs, dinv, R2, w2, 0, 0);
  conv2_prop_kernel<<<NPB, 256, 0, stream>>>(Q2, P2, nullptr, csr, offs, dinv, R2, w2, 1, 0);
  conv2_prop_kernel<<<NPB, 256, 0, stream>>>(P2, Q2, nullptr, csr, offs, dinv, R2, w2, 1, 0);
  conv2_prop_kernel<<<NPB, 256, 0, stream>>>(Q2, P2, y, csr, offs, dinv, R2, w2, 1, 1);
}

// Round 14
// 500.732 us; speedup vs baseline: 1.7283x; 1.0426x over previous
//
#include <hip/hip_runtime.h>
#include <math.h>

#define N_NODES 100000
#define N_EDGES 3200000
#define KH 48            // K*H active channels
#define FDIM 64          // padded feature row stride (128 B, line-aligned)
#define NH 16            // H
#define BN_EPS 1e-5f
#define NBUCK 196        // ceil(100000/512) buckets of 512 nodes
#define BSHIFT 9
#define BMASK 511
#define EPB 16384        // edges per block in bucket kernels
#define NBLK1 196        // ceil(N_EDGES/EPB)
#define FIX 16777216.0f  // 2^24 fixed point for degree sums

typedef unsigned long long u64;
typedef unsigned int u32;
typedef unsigned short u16;

__device__ __forceinline__ u16 f2bf(float f) {
  u32 b = __float_as_uint(f);
  b += 0x7FFFu + ((b >> 16) & 1u);   // RNE
  return (u16)(b >> 16);
}
__device__ __forceinline__ float bf2f(u32 s) {
  return __uint_as_float(s << 16);
}

// ---------------- K1: per-block LDS bucket histogram -> global totals -------
__global__ __launch_bounds__(256) void bucket_count_kernel(
    const int* __restrict__ col, u32* __restrict__ btot /* stride 8 */) {
  __shared__ u32 bins[NBUCK];
  for (int t = threadIdx.x; t < NBUCK; t += 256) bins[t] = 0;
  __syncthreads();
  int eb = blockIdx.x * EPB;
  for (int it = 0; it < EPB / 256; ++it) {
    int e = eb + it * 256 + threadIdx.x;
    if (e < N_EDGES) atomicAdd(&bins[col[e] >> BSHIFT], 1u);
  }
  __syncthreads();
  for (int t = threadIdx.x; t < NBUCK; t += 256)
    if (bins[t]) atomicAdd(&btot[t * 8], bins[t]);
}

// ---------------- K2: scan bucket totals -> starts, init cursors ------------
__global__ __launch_bounds__(256) void bucket_scan_kernel(
    const u32* __restrict__ btot, u32* __restrict__ bstart, u32* __restrict__ gcur,
    int* __restrict__ offs) {
  __shared__ u32 sh[256];
  int t = threadIdx.x;
  u32 v = (t < NBUCK) ? btot[t * 8] : 0;
  sh[t] = v;
  __syncthreads();
  for (int d = 1; d < 256; d <<= 1) {
    u32 u = (t >= d) ? sh[t - d] : 0;
    __syncthreads();
    sh[t] += u;
    __syncthreads();
  }
  if (t < NBUCK) { u32 s = sh[t] - v; bstart[t] = s; gcur[t * 8] = s; }
  if (t == NBUCK) bstart[NBUCK] = N_EDGES;
  if (t == 0) offs[N_NODES] = N_EDGES;
}

// ---------------- K3: scatter edges into bucket-major order -----------------
__global__ __launch_bounds__(256) void bucket_scatter_kernel(
    const int* __restrict__ row, const int* __restrict__ col,
    const float* __restrict__ ea, u32* __restrict__ gcur,
    int2* __restrict__ bucketed) {
  __shared__ u32 bins[NBUCK];
  __shared__ u32 base[NBUCK];
  __shared__ u16 rnk[EPB];
  for (int t = threadIdx.x; t < NBUCK; t += 256) bins[t] = 0;
  __syncthreads();
  int eb = blockIdx.x * EPB;
  for (int it = 0; it < EPB / 256; ++it) {
    int i = it * 256 + threadIdx.x;
    int e = eb + i;
    if (e < N_EDGES) rnk[i] = (u16)atomicAdd(&bins[col[e] >> BSHIFT], 1u);
  }
  __syncthreads();
  for (int t = threadIdx.x; t < NBUCK; t += 256) {
    u32 c = bins[t];
    if (c) base[t] = atomicAdd(&gcur[t * 8], c);
  }
  __syncthreads();
  for (int it = 0; it < EPB / 256; ++it) {
    int i = it * 256 + threadIdx.x;
    int e = eb + i;
    if (e < N_EDGES) {
      int c = col[e];
      int bkt = c >> BSHIFT, cl = c & BMASK;
      u32 pos = base[bkt] + (u32)rnk[i];
      bucketed[pos] = make_int2((cl << 17) | row[e], __float_as_int(ea[e]));
    }
  }
}

// ---------------- P2a: per-bucket node counts -> offs, dinv, zx -------------
__global__ __launch_bounds__(1024) void node_offs_kernel(
    const int2* __restrict__ bucketed, const u32* __restrict__ bstart,
    const float* __restrict__ x,
    int* __restrict__ offs, float* __restrict__ dinv, u16* __restrict__ zx) {
  __shared__ u32 cnt[512];
  __shared__ u32 degf[512];
  int t = threadIdx.x;
  if (t < 512) { cnt[t] = 0; degf[t] = 0; }
  __syncthreads();
  int b = blockIdx.x;
  u32 s = bstart[b], e = bstart[b + 1];
  for (u32 i = s + t; i < e; i += 1024) {
    int2 v = bucketed[i];
    int cl = (v.x >> 17) & BMASK;
    atomicAdd(&cnt[cl], 1u);
    atomicAdd(&degf[cl], (u32)(__int_as_float(v.y) * FIX));
  }
  __syncthreads();
  u32 v0 = (t < 512) ? cnt[t] : 0;
  for (int d = 1; d < 512; d <<= 1) {
    u32 u = (t < 512 && t >= d) ? cnt[t - d] : 0;
    __syncthreads();
    if (t < 512) cnt[t] += u;
    __syncthreads();
  }
  int n = b * 512 + t;
  if (t < 512 && n < N_NODES) {
    offs[n] = (int)(s + cnt[t] - v0);  // exclusive
    float dg = (float)degf[t] * (1.0f / FIX);
    float dv = dg > 0.f ? rsqrtf(fmaxf(dg, 1e-12f)) : 0.f;
    dinv[n] = dv;
    zx[n] = f2bf(x[n] * dv);
  }
}

// ---------------- P2b: packed 4B CSR: (src<<15) | bf16(ea) ------------------
__global__ __launch_bounds__(1024) void csr_fill_kernel(
    const int2* __restrict__ bucketed, const u32* __restrict__ bstart,
    const int* __restrict__ offs, u32* __restrict__ csr) {
  __shared__ u32 cur[512];
  int t = threadIdx.x;
  int b = blockIdx.x;
  int n = b * 512 + t;
  if (t < 512) cur[t] = (n < N_NODES) ? (u32)offs[n] : 0;
  __syncthreads();
  u32 s = bstart[b], e = bstart[b + 1];
  for (u32 i = s + t; i < e; i += 1024) {
    int2 v = bucketed[i];
    int cl = (v.x >> 17) & BMASK;
    u32 r = (u32)(v.x & 0x1FFFF);
    u16 w = f2bf(__int_as_float(v.y));   // ea >= 0 -> sign bit 0, w < 0x8000
    u32 pos = atomicAdd(&cur[cl], 1u);
    csr[pos] = (r << 15) | (u32)w;
  }
}

// ---------------- layer-1: scalar prop + epilogue + transform (merged) ------
__global__ __launch_bounds__(256) void sprop_mid_kernel(
    const u32* __restrict__ csr, const int* __restrict__ offs,
    const u16* __restrict__ zx, const float* __restrict__ dinv,
    const float* __restrict__ x,
    const float* __restrict__ w1i, const float* __restrict__ w1r,
    const float* __restrict__ b1, const float* __restrict__ w1,
    u16* __restrict__ tout) {
  int t = blockIdx.x * 256 + threadIdx.x;
  int n = t >> 4, c = t & 15;
  float a = 0.f;
  int s = offs[n], e = offs[n + 1];
  for (int i = s + c; i < e; i += 16) {
    u32 ee = csr[i];
    a += bf2f(ee & 0x7FFFu) * bf2f((u32)zx[ee >> 15]);
  }
#pragma unroll
  for (int o = 8; o; o >>= 1) a += __shfl_xor(a, o, 64);
  float dn = dinv[n];
  float sn = a * dn;
  float xn = x[n];
  int base = (threadIdx.x & 63) & 48;
#pragma unroll
  for (int k = 0; k < 3; ++k) {
    float u = fmaxf(sn * w1i[k * 16 + c] + xn * w1r[k * 16 + c] + b1[k * 16 + c], 0.f);
    float tf = 0.f;
#pragma unroll
    for (int f = 0; f < 16; ++f) tf += __shfl(u, base + f, 64) * w1[k * 256 + f * 16 + c];
    tout[(size_t)n * FDIM + k * 16 + c] = f2bf(tf * dn);
  }
}

// ---------------- conv1 propagate, all 3 stacks combined --------------------
// wave per node, lane = channel, 48 active; rows 128 B line-aligned.
// EXPLICIT-SCALAR unroll-16 tier (32 named scalars -> true VGPRs, no scratch),
// then the R10-proven 8/4/scalar ladder. All unmasked. nt CSR loads.
__global__ __launch_bounds__(256) void conv1_prop_kernel(
    const u16* __restrict__ tin, u16* __restrict__ tout, float* __restrict__ hbuf,
    const u32* __restrict__ csr, const int* __restrict__ offs,
    const float* __restrict__ dinv, const float* __restrict__ x,
    const float* __restrict__ w1r, const float* __restrict__ b1,
    const float* __restrict__ w1, int do_t) {
  int lane = threadIdx.x & 63;
  int wid = (blockIdx.x * blockDim.x + threadIdx.x) >> 6;
  int nw = (gridDim.x * blockDim.x) >> 6;
  int c = lane;
  bool act = c < KH;
  float rb = act ? w1r[c] : 0.f;
  float bb = act ? b1[c] : 0.f;
  float wreg[16];
  if (do_t) {
    int k = c >> 4, o = c & 15;
    if (act) {
#pragma unroll
      for (int f = 0; f < 16; ++f) wreg[f] = w1[k * 256 + f * 16 + o];
    } else {
#pragma unroll
      for (int f = 0; f < 16; ++f) wreg[f] = 0.f;
    }
  }
  for (int n = wid; n < N_NODES; n += nw) {
    int nu = __builtin_amdgcn_readfirstlane(n);
    int s = offs[nu], e = offs[nu + 1];
    float acc = 0.f;
    int i = s;
    for (; i + 16 <= e; i += 16) {
      u32 e0 = __builtin_nontemporal_load(&csr[i]);
      u32 e1 = __builtin_nontemporal_load(&csr[i + 1]);
      u32 e2 = __builtin_nontemporal_load(&csr[i + 2]);
      u32 e3 = __builtin_nontemporal_load(&csr[i + 3]);
      u32 e4 = __builtin_nontemporal_load(&csr[i + 4]);
      u32 e5 = __builtin_nontemporal_load(&csr[i + 5]);
      u32 e6 = __builtin_nontemporal_load(&csr[i + 6]);
      u32 e7 = __builtin_nontemporal_load(&csr[i + 7]);
      u32 e8 = __builtin_nontemporal_load(&csr[i + 8]);
      u32 e9 = __builtin_nontemporal_load(&csr[i + 9]);
      u32 ea0 = __builtin_nontemporal_load(&csr[i + 10]);
      u32 eb0 = __builtin_nontemporal_load(&csr[i + 11]);
      u32 ec0 = __builtin_nontemporal_load(&csr[i + 12]);
      u32 ed0 = __builtin_nontemporal_load(&csr[i + 13]);
      u32 ee0 = __builtin_nontemporal_load(&csr[i + 14]);
      u32 ef0 = __builtin_nontemporal_load(&csr[i + 15]);
      float v0 = 0.f, v1 = 0.f, v2 = 0.f, v3 = 0.f;
      float v4 = 0.f, v5 = 0.f, v6 = 0.f, v7 = 0.f;
      float v8 = 0.f, v9 = 0.f, va = 0.f, vb = 0.f;
      float vc = 0.f, vd = 0.f, ve = 0.f, vf = 0.f;
      if (act) {
        v0 = bf2f((u32)tin[(e0 >> 15) * FDIM + c]);
        v1 = bf2f((u32)tin[(e1 >> 15) * FDIM + c]);
        v2 = bf2f((u32)tin[(e2 >> 15) * FDIM + c]);
        v3 = bf2f((u32)tin[(e3 >> 15) * FDIM + c]);
        v4 = bf2f((u32)tin[(e4 >> 15) * FDIM + c]);
        v5 = bf2f((u32)tin[(e5 >> 15) * FDIM + c]);
        v6 = bf2f((u32)tin[(e6 >> 15) * FDIM + c]);
        v7 = bf2f((u32)tin[(e7 >> 15) * FDIM + c]);
        v8 = bf2f((u32)tin[(e8 >> 15) * FDIM + c]);
        v9 = bf2f((u32)tin[(e9 >> 15) * FDIM + c]);
        va = bf2f((u32)tin[(ea0 >> 15) * FDIM + c]);
        vb = bf2f((u32)tin[(eb0 >> 15) * FDIM + c]);
        vc = bf2f((u32)tin[(ec0 >> 15) * FDIM + c]);
        vd = bf2f((u32)tin[(ed0 >> 15) * FDIM + c]);
        ve = bf2f((u32)tin[(ee0 >> 15) * FDIM + c]);
        vf = bf2f((u32)tin[(ef0 >> 15) * FDIM + c]);
      }
      acc += bf2f(e0 & 0x7FFFu) * v0 + bf2f(e1 & 0x7FFFu) * v1 +
             bf2f(e2 & 0x7FFFu) * v2 + bf2f(e3 & 0x7FFFu) * v3 +
             bf2f(e4 & 0x7FFFu) * v4 + bf2f(e5 & 0x7FFFu) * v5 +
             bf2f(e6 & 0x7FFFu) * v6 + bf2f(e7 & 0x7FFFu) * v7 +
             bf2f(e8 & 0x7FFFu) * v8 + bf2f(e9 & 0x7FFFu) * v9 +
             bf2f(ea0 & 0x7FFFu) * va + bf2f(eb0 & 0x7FFFu) * vb +
             bf2f(ec0 & 0x7FFFu) * vc + bf2f(ed0 & 0x7FFFu) * vd +
             bf2f(ee0 & 0x7FFFu) * ve + bf2f(ef0 & 0x7FFFu) * vf;
    }
    for (; i + 8 <= e; i += 8) {
      u32 e0 = __builtin_nontemporal_load(&csr[i]);
      u32 e1 = __builtin_nontemporal_load(&csr[i + 1]);
      u32 e2 = __builtin_nontemporal_load(&csr[i + 2]);
      u32 e3 = __builtin_nontemporal_load(&csr[i + 3]);
      u32 e4 = __builtin_nontemporal_load(&csr[i + 4]);
      u32 e5 = __builtin_nontemporal_load(&csr[i + 5]);
      u32 e6 = __builtin_nontemporal_load(&csr[i + 6]);
      u32 e7 = __builtin_nontemporal_load(&csr[i + 7]);
      float v0 = 0.f, v1 = 0.f, v2 = 0.f, v3 = 0.f;
      float v4 = 0.f, v5 = 0.f, v6 = 0.f, v7 = 0.f;
      if (act) {
        v0 = bf2f((u32)tin[(e0 >> 15) * FDIM + c]);
        v1 = bf2f((u32)tin[(e1 >> 15) * FDIM + c]);
        v2 = bf2f((u32)tin[(e2 >> 15) * FDIM + c]);
        v3 = bf2f((u32)tin[(e3 >> 15) * FDIM + c]);
        v4 = bf2f((u32)tin[(e4 >> 15) * FDIM + c]);
        v5 = bf2f((u32)tin[(e5 >> 15) * FDIM + c]);
        v6 = bf2f((u32)tin[(e6 >> 15) * FDIM + c]);
        v7 = bf2f((u32)tin[(e7 >> 15) * FDIM + c]);
      }
      acc += bf2f(e0 & 0x7FFFu) * v0 + bf2f(e1 & 0x7FFFu) * v1 +
             bf2f(e2 & 0x7FFFu) * v2 + bf2f(e3 & 0x7FFFu) * v3 +
             bf2f(e4 & 0x7FFFu) * v4 + bf2f(e5 & 0x7FFFu) * v5 +
             bf2f(e6 & 0x7FFFu) * v6 + bf2f(e7 & 0x7FFFu) * v7;
    }
    for (; i + 4 <= e; i += 4) {
      u32 e0 = __builtin_nontemporal_load(&csr[i]);
      u32 e1 = __builtin_nontemporal_load(&csr[i + 1]);
      u32 e2 = __builtin_nontemporal_load(&csr[i + 2]);
      u32 e3 = __builtin_nontemporal_load(&csr[i + 3]);
      float v0 = 0.f, v1 = 0.f, v2 = 0.f, v3 = 0.f;
      if (act) {
        v0 = bf2f((u32)tin[(e0 >> 15) * FDIM + c]);
        v1 = bf2f((u32)tin[(e1 >> 15) * FDIM + c]);
        v2 = bf2f((u32)tin[(e2 >> 15) * FDIM + c]);
        v3 = bf2f((u32)tin[(e3 >> 15) * FDIM + c]);
      }
      acc += bf2f(e0 & 0x7FFFu) * v0 + bf2f(e1 & 0x7FFFu) * v1 +
             bf2f(e2 & 0x7FFFu) * v2 + bf2f(e3 & 0x7FFFu) * v3;
    }
    for (; i < e; ++i) {
      u32 ee = __builtin_nontemporal_load(&csr[i]);
      if (act) acc += bf2f(ee & 0x7FFFu) * bf2f((u32)tin[(ee >> 15) * FDIM + c]);
    }
    float dn = dinv[nu];
    float u = fmaxf(acc * dn + x[nu] * rb + bb, 0.f);
    if (do_t) {
      float tf = 0.f;
      int base = c & 48;
#pragma unroll
      for (int f = 0; f < 16; ++f) tf += __shfl(u, base + f, 64) * wreg[f];
      if (act) tout[(size_t)nu * FDIM + c] = f2bf(tf * dn);
    } else {
      float m1v = __shfl(u, lane + 16, 64);
      float m2v = __shfl(u, lane + 32, 64);
      if (lane < NH) hbuf[(size_t)nu * NH + lane] = (u + m1v + m2v) * (1.f / 3.f);
    }
  }
}

// ---------------- BN stats over hbuf [N,16] ---------------------------------
__global__ __launch_bounds__(256) void bn_stats_kernel(
    const float* __restrict__ h, double* __restrict__ stats) {
  __shared__ float ssum[NH], ssq[NH];
  int tid = threadIdx.x;
  if (tid < NH) { ssum[tid] = 0.f; ssq[tid] = 0.f; }
  __syncthreads();
  int n = blockIdx.x * blockDim.x + tid;
  bool valid = n < N_NODES;
  const float4* p = (const float4*)(h + (size_t)(valid ? n : 0) * NH);
  float hv[NH];
#pragma unroll
  for (int q = 0; q < 4; ++q) {
    float4 v = valid ? p[q] : make_float4(0.f, 0.f, 0.f, 0.f);
    hv[q * 4 + 0] = v.x; hv[q * 4 + 1] = v.y; hv[q * 4 + 2] = v.z; hv[q * 4 + 3] = v.w;
  }
#pragma unroll
  for (int f = 0; f < NH; ++f) {
    float s = hv[f], q = hv[f] * hv[f];
    for (int o = 32; o; o >>= 1) { s += __shfl_xor(s, o, 64); q += __shfl_xor(q, o, 64); }
    if ((tid & 63) == 0) { atomicAdd(&ssum[f], s); atomicAdd(&ssq[f], q); }
  }
  __syncthreads();
  if (tid < NH) {
    atomicAdd(&stats[tid], (double)ssum[tid]);
    atomicAdd(&stats[NH + tid], (double)ssq[tid]);
  }
}

__global__ __launch_bounds__(64) void bn_final_kernel(
    const double* __restrict__ stats, const float* __restrict__ g,
    const float* __restrict__ b, float* __restrict__ sc, float* __restrict__ sh) {
  int f = threadIdx.x;
  if (f < NH) {
    double mu = stats[f] / (double)N_NODES;
    double var = stats[NH + f] / (double)N_NODES - mu * mu;
    float scale = g[f] * (float)(1.0 / sqrt(var + (double)BN_EPS));
    sc[f] = scale;
    sh[f] = b[f] - (float)mu * scale;
  }
}

// ---------------- conv2 init: BN-apply + relu + init/root dots --------------
__global__ __launch_bounds__(256) void conv2_init_kernel(
    const float* __restrict__ h, const float* __restrict__ sc, const float* __restrict__ sh,
    const float* __restrict__ dinv,
    const float* __restrict__ w2i, const float* __restrict__ w2r, const float* __restrict__ b2,
    float* __restrict__ P, float* __restrict__ R) {
  int n = blockIdx.x * blockDim.x + threadIdx.x;
  if (n >= N_NODES) return;
  float u[NH];
#pragma unroll
  for (int f = 0; f < NH; ++f) u[f] = fmaxf(h[(size_t)n * NH + f] * sc[f] + sh[f], 0.f);
  float dn = dinv[n];
#pragma unroll
  for (int k = 0; k < 3; ++k) {
    float r = b2[k], o = 0.f;
#pragma unroll
    for (int f = 0; f < NH; ++f) {
      r += u[f] * w2r[k * NH + f];
      o += u[f] * w2i[k * NH + f];
    }
    R[n * 4 + k] = r;
    P[n * 4 + k] = o * dn;
  }
  R[n * 4 + 3] = 0.f;
  P[n * 4 + 3] = 0.f;
}

// ---------------- conv2 propagate: 16-lane groups, packed CSR ---------------
__global__ __launch_bounds__(256) void conv2_prop_kernel(
    const float* __restrict__ in4, float* __restrict__ out4, float* __restrict__ y,
    const u32* __restrict__ csr, const int* __restrict__ offs,
    const float* __restrict__ dinv,
    const float* __restrict__ R, const float* __restrict__ w2,
    int scale_w2, int final_out) {
  int t = blockIdx.x * 256 + threadIdx.x;
  int n = t >> 4, sub = t & 15;
  float m0 = 1.f, m1 = 1.f, m2 = 1.f;
  if (scale_w2) { m0 = w2[0]; m1 = w2[1]; m2 = w2[2]; }
  int s = offs[n], e = offs[n + 1];
  float a0 = 0.f, a1 = 0.f, a2 = 0.f;
  for (int i = s + sub; i < e; i += 16) {
    u32 ee = csr[i];
    float w = bf2f(ee & 0x7FFFu);
    const float4 v = *(const float4*)(in4 + (size_t)(ee >> 15) * 4);
    a0 += w * v.x;
    a1 += w * v.y;
    a2 += w * v.z;
  }
#pragma unroll
  for (int o = 8; o; o >>= 1) {
    a0 += __shfl_xor(a0, o, 64);
    a1 += __shfl_xor(a1, o, 64);
    a2 += __shfl_xor(a2, o, 64);
  }
  if (sub == 0) {
    float dn = dinv[n];
    a0 = a0 * dn * m0 + R[n * 4 + 0];
    a1 = a1 * dn * m1 + R[n * 4 + 1];
    a2 = a2 * dn * m2 + R[n * 4 + 2];
    if (final_out) {
      float sm = (a0 + a1 + a2) * (1.f / 3.f);
      y[n] = 1.f / (1.f + expf(-sm));
    } else {
      out4[n * 4 + 0] = a0 * dn;
      out4[n * 4 + 1] = a1 * dn;
      out4[n * 4 + 2] = a2 * dn;
      out4[n * 4 + 3] = 0.f;
    }
  }
}

extern "C" void kernel_launch(void* const* d_in, const int* in_sizes, int n_in,
                              void* d_out, int out_size, void* d_ws, size_t ws_size,
                              hipStream_t stream) {
  const float* x   = (const float*)d_in[0];
  const int*   ei  = (const int*)d_in[1];
  const float* ea  = (const float*)d_in[2];
  // d_in[3] = batch (unused)
  const float* w1i = (const float*)d_in[4];
  const float* w1  = (const float*)d_in[5];
  const float* w1r = (const float*)d_in[6];
  const float* b1  = (const float*)d_in[7];
  const float* bng = (const float*)d_in[8];
  const float* bnb = (const float*)d_in[9];
  const float* w2i = (const float*)d_in[10];
  const float* w2  = (const float*)d_in[11];
  const float* w2r = (const float*)d_in[12];
  const float* b2  = (const float*)d_in[13];
  float* y = (float*)d_out;

  const int* row = ei;
  const int* col = ei + N_EDGES;

  char* ws = (char*)d_ws;
  size_t off = 0;
  auto alloc = [&](size_t bytes) -> char* {
    char* p = ws + off;
    off += (bytes + 255) & ~(size_t)255;
    return p;
  };
  u32*    btot   = (u32*)alloc((size_t)NBUCK * 8 * 4);
  u32*    gcur   = (u32*)alloc((size_t)NBUCK * 8 * 4);
  u32*    bstart = (u32*)alloc((size_t)(NBUCK + 1) * 4);
  int*    offs   = (int*)alloc((size_t)(N_NODES + 1) * 4);
  float*  dinv   = (float*)alloc((size_t)N_NODES * 4);
  u16*    zx     = (u16*)alloc((size_t)N_NODES * 2);
  double* stats  = (double*)alloc(32 * 8);
  float*  bnsc   = (float*)alloc(16 * 4);
  float*  bnsh   = (float*)alloc(16 * 4);
  int2*   bucketed = (int2*)alloc((size_t)N_EDGES * 8);
  u32*    csr    = (u32*)alloc((size_t)N_EDGES * 4);
  u16*    tA     = (u16*)alloc((size_t)N_NODES * FDIM * 2);
  u16*    tB     = (u16*)alloc((size_t)N_NODES * FDIM * 2);
  float*  hbuf   = (float*)alloc((size_t)N_NODES * NH * 4);
  float*  P2     = (float*)alloc((size_t)N_NODES * 4 * 4);
  float*  Q2     = (float*)alloc((size_t)N_NODES * 4 * 4);
  float*  R2     = (float*)alloc((size_t)N_NODES * 4 * 4);
  (void)ws_size; (void)in_sizes; (void)n_in; (void)out_size;

  hipMemsetAsync(btot, 0, (size_t)NBUCK * 8 * 4, stream);
  hipMemsetAsync(stats, 0, 32 * 8, stream);

  bucket_count_kernel<<<NBLK1, 256, 0, stream>>>(col, btot);
  bucket_scan_kernel<<<1, 256, 0, stream>>>(btot, bstart, gcur, offs);
  bucket_scatter_kernel<<<NBLK1, 256, 0, stream>>>(row, col, ea, gcur, bucketed);
  node_offs_kernel<<<NBUCK, 1024, 0, stream>>>(bucketed, bstart, x, offs, dinv, zx);
  csr_fill_kernel<<<NBUCK, 1024, 0, stream>>>(bucketed, bstart, offs, csr);

  const int NPB = 6250;  // N_NODES*16/256 exactly
  // conv1 layer 1 (rank-1 collapse): merged scalar prop + dense epilogue -> tA
  sprop_mid_kernel<<<NPB, 256, 0, stream>>>(csr, offs, zx, dinv, x, w1i, w1r, b1, w1, tA);
  // conv1 layers 2-4: combined 3-stack propagation; 6250 blocks = 4 nodes/wave
  conv1_prop_kernel<<<6250, 256, 0, stream>>>(tA, tB, nullptr, csr, offs, dinv, x, w1r, b1, w1, 1);
  conv1_prop_kernel<<<6250, 256, 0, stream>>>(tB, tA, nullptr, csr, offs, dinv, x, w1r, b1, w1, 1);
  conv1_prop_kernel<<<6250, 256, 0, stream>>>(tA, nullptr, hbuf, csr, offs, dinv, x, w1r, b1, w1, 0);

  bn_stats_kernel<<<(N_NODES + 255) / 256, 256, 0, stream>>>(hbuf, stats);
  bn_final_kernel<<<1, 64, 0, stream>>>(stats, bng, bnb, bnsc, bnsh);
  conv2_init_kernel<<<(N_NODES + 255) / 256, 256, 0, stream>>>(
      hbuf, bnsc, bnsh, dinv, w2i, w2r, b2, P2, R2);

  conv2_prop_kernel<<<NPB, 256, 0, stream>>>(P2, Q2, nullptr, csr, offs, dinv, R2, w2, 0, 0);
  conv2_prop_kernel<<<NPB, 256, 0, stream>>>(Q2, P2, nullptr, csr, offs, dinv, R2, w2, 1, 0);
  conv2_prop_kernel<<<NPB, 256, 0, stream>>>(P2, Q2, nullptr, csr, offs, dinv, R2, w2, 1, 0);
  conv2_prop_kernel<<<NPB, 256, 0, stream>>>(Q2, P2, y, csr, offs, dinv, R2, w2, 1, 1);
}

// Round 15
// 493.833 us; speedup vs baseline: 1.7525x; 1.0140x over previous
//
#include <hip/hip_runtime.h>
#include <math.h>

#define N_NODES 100000
#define N_EDGES 3200000
#define KH 48            // K*H active channels
#define FDIM 64          // padded feature row stride (128 B, line-aligned)
#define NH 16            // H
#define BN_EPS 1e-5f
#define NBUCK 196        // ceil(100000/512) buckets of 512 nodes
#define BSHIFT 9
#define BMASK 511
#define EPB 16384        // edges per block in bucket kernels
#define NBLK1 196        // ceil(N_EDGES/EPB)
#define FIX 16777216.0f  // 2^24 fixed point for degree sums

typedef unsigned long long u64;
typedef unsigned int u32;
typedef unsigned short u16;

__device__ __forceinline__ u16 f2bf(float f) {
  u32 b = __float_as_uint(f);
  b += 0x7FFFu + ((b >> 16) & 1u);   // RNE
  return (u16)(b >> 16);
}
__device__ __forceinline__ float bf2f(u32 s) {
  return __uint_as_float(s << 16);
}

// ---------------- K1: per-block LDS bucket histogram -> global totals -------
// 1024 threads: 196 blocks x 16 waves (was 4) -> 4x resident waves.
__global__ __launch_bounds__(1024) void bucket_count_kernel(
    const int* __restrict__ col, u32* __restrict__ btot /* stride 8 */) {
  __shared__ u32 bins[NBUCK];
  for (int t = threadIdx.x; t < NBUCK; t += 1024) bins[t] = 0;
  __syncthreads();
  int eb = blockIdx.x * EPB;
  for (int it = 0; it < EPB / 1024; ++it) {
    int e = eb + it * 1024 + threadIdx.x;
    if (e < N_EDGES) atomicAdd(&bins[col[e] >> BSHIFT], 1u);
  }
  __syncthreads();
  for (int t = threadIdx.x; t < NBUCK; t += 1024)
    if (bins[t]) atomicAdd(&btot[t * 8], bins[t]);
}

// ---------------- K2: scan bucket totals -> starts, init cursors ------------
__global__ __launch_bounds__(256) void bucket_scan_kernel(
    const u32* __restrict__ btot, u32* __restrict__ bstart, u32* __restrict__ gcur,
    int* __restrict__ offs) {
  __shared__ u32 sh[256];
  int t = threadIdx.x;
  u32 v = (t < NBUCK) ? btot[t * 8] : 0;
  sh[t] = v;
  __syncthreads();
  for (int d = 1; d < 256; d <<= 1) {
    u32 u = (t >= d) ? sh[t - d] : 0;
    __syncthreads();
    sh[t] += u;
    __syncthreads();
  }
  if (t < NBUCK) { u32 s = sh[t] - v; bstart[t] = s; gcur[t * 8] = s; }
  if (t == NBUCK) bstart[NBUCK] = N_EDGES;
  if (t == 0) offs[N_NODES] = N_EDGES;
}

// ---------------- K3: scatter edges into bucket-major order -----------------
// 1024 threads: fixes the 7.6%-occupancy latency bind (196 blocks only).
__global__ __launch_bounds__(1024) void bucket_scatter_kernel(
    const int* __restrict__ row, const int* __restrict__ col,
    const float* __restrict__ ea, u32* __restrict__ gcur,
    int2* __restrict__ bucketed) {
  __shared__ u32 bins[NBUCK];
  __shared__ u32 base[NBUCK];
  __shared__ u16 rnk[EPB];
  for (int t = threadIdx.x; t < NBUCK; t += 1024) bins[t] = 0;
  __syncthreads();
  int eb = blockIdx.x * EPB;
  for (int it = 0; it < EPB / 1024; ++it) {
    int i = it * 1024 + threadIdx.x;
    int e = eb + i;
    if (e < N_EDGES) rnk[i] = (u16)atomicAdd(&bins[col[e] >> BSHIFT], 1u);
  }
  __syncthreads();
  for (int t = threadIdx.x; t < NBUCK; t += 1024) {
    u32 c = bins[t];
    if (c) base[t] = atomicAdd(&gcur[t * 8], c);
  }
  __syncthreads();
  for (int it = 0; it < EPB / 1024; ++it) {
    int i = it * 1024 + threadIdx.x;
    int e = eb + i;
    if (e < N_EDGES) {
      int c = col[e];
      int bkt = c >> BSHIFT, cl = c & BMASK;
      u32 pos = base[bkt] + (u32)rnk[i];
      bucketed[pos] = make_int2((cl << 17) | row[e], __float_as_int(ea[e]));
    }
  }
}

// ---------------- P2a: per-bucket node counts -> offs, dinv, zx -------------
__global__ __launch_bounds__(1024) void node_offs_kernel(
    const int2* __restrict__ bucketed, const u32* __restrict__ bstart,
    const float* __restrict__ x,
    int* __restrict__ offs, float* __restrict__ dinv, u16* __restrict__ zx) {
  __shared__ u32 cnt[512];
  __shared__ u32 degf[512];
  int t = threadIdx.x;
  if (t < 512) { cnt[t] = 0; degf[t] = 0; }
  __syncthreads();
  int b = blockIdx.x;
  u32 s = bstart[b], e = bstart[b + 1];
  for (u32 i = s + t; i < e; i += 1024) {
    int2 v = bucketed[i];
    int cl = (v.x >> 17) & BMASK;
    atomicAdd(&cnt[cl], 1u);
    atomicAdd(&degf[cl], (u32)(__int_as_float(v.y) * FIX));
  }
  __syncthreads();
  u32 v0 = (t < 512) ? cnt[t] : 0;
  for (int d = 1; d < 512; d <<= 1) {
    u32 u = (t < 512 && t >= d) ? cnt[t - d] : 0;
    __syncthreads();
    if (t < 512) cnt[t] += u;
    __syncthreads();
  }
  int n = b * 512 + t;
  if (t < 512 && n < N_NODES) {
    offs[n] = (int)(s + cnt[t] - v0);  // exclusive
    float dg = (float)degf[t] * (1.0f / FIX);
    float dv = dg > 0.f ? rsqrtf(fmaxf(dg, 1e-12f)) : 0.f;
    dinv[n] = dv;
    zx[n] = f2bf(x[n] * dv);
  }
}

// ---------------- P2b: packed 4B CSR: (src<<15) | bf16(ea) ------------------
__global__ __launch_bounds__(1024) void csr_fill_kernel(
    const int2* __restrict__ bucketed, const u32* __restrict__ bstart,
    const int* __restrict__ offs, u32* __restrict__ csr) {
  __shared__ u32 cur[512];
  int t = threadIdx.x;
  int b = blockIdx.x;
  int n = b * 512 + t;
  if (t < 512) cur[t] = (n < N_NODES) ? (u32)offs[n] : 0;
  __syncthreads();
  u32 s = bstart[b], e = bstart[b + 1];
  for (u32 i = s + t; i < e; i += 1024) {
    int2 v = bucketed[i];
    int cl = (v.x >> 17) & BMASK;
    u32 r = (u32)(v.x & 0x1FFFF);
    u16 w = f2bf(__int_as_float(v.y));   // ea >= 0 -> sign bit 0, w < 0x8000
    u32 pos = atomicAdd(&cur[cl], 1u);
    csr[pos] = (r << 15) | (u32)w;
  }
}

// ---------------- layer-1: scalar prop + epilogue + transform (merged) ------
__global__ __launch_bounds__(256) void sprop_mid_kernel(
    const u32* __restrict__ csr, const int* __restrict__ offs,
    const u16* __restrict__ zx, const float* __restrict__ dinv,
    const float* __restrict__ x,
    const float* __restrict__ w1i, const float* __restrict__ w1r,
    const float* __restrict__ b1, const float* __restrict__ w1,
    u16* __restrict__ tout) {
  int t = blockIdx.x * 256 + threadIdx.x;
  int n = t >> 4, c = t & 15;
  float a = 0.f;
  int s = offs[n], e = offs[n + 1];
  for (int i = s + c; i < e; i += 16) {
    u32 ee = csr[i];
    a += bf2f(ee & 0x7FFFu) * bf2f((u32)zx[ee >> 15]);
  }
#pragma unroll
  for (int o = 8; o; o >>= 1) a += __shfl_xor(a, o, 64);
  float dn = dinv[n];
  float sn = a * dn;
  float xn = x[n];
  int base = (threadIdx.x & 63) & 48;
#pragma unroll
  for (int k = 0; k < 3; ++k) {
    float u = fmaxf(sn * w1i[k * 16 + c] + xn * w1r[k * 16 + c] + b1[k * 16 + c], 0.f);
    float tf = 0.f;
#pragma unroll
    for (int f = 0; f < 16; ++f) tf += __shfl(u, base + f, 64) * w1[k * 256 + f * 16 + c];
    tout[(size_t)n * FDIM + k * 16 + c] = f2bf(tf * dn);
  }
}

// ---------------- conv1 propagate, all 3 stacks combined --------------------
// wave per node, lane = channel, 48 active; rows 128 B line-aligned.
// EXPLICIT-SCALAR unroll-16 tier, then 8/4/scalar ladder. All unmasked.
__global__ __launch_bounds__(256) void conv1_prop_kernel(
    const u16* __restrict__ tin, u16* __restrict__ tout, float* __restrict__ hbuf,
    const u32* __restrict__ csr, const int* __restrict__ offs,
    const float* __restrict__ dinv, const float* __restrict__ x,
    const float* __restrict__ w1r, const float* __restrict__ b1,
    const float* __restrict__ w1, int do_t) {
  int lane = threadIdx.x & 63;
  int wid = (blockIdx.x * blockDim.x + threadIdx.x) >> 6;
  int nw = (gridDim.x * blockDim.x) >> 6;
  int c = lane;
  bool act = c < KH;
  float rb = act ? w1r[c] : 0.f;
  float bb = act ? b1[c] : 0.f;
  float wreg[16];
  if (do_t) {
    int k = c >> 4, o = c & 15;
    if (act) {
#pragma unroll
      for (int f = 0; f < 16; ++f) wreg[f] = w1[k * 256 + f * 16 + o];
    } else {
#pragma unroll
      for (int f = 0; f < 16; ++f) wreg[f] = 0.f;
    }
  }
  for (int n = wid; n < N_NODES; n += nw) {
    int nu = __builtin_amdgcn_readfirstlane(n);
    int s = offs[nu], e = offs[nu + 1];
    float acc = 0.f;
    int i = s;
    for (; i + 16 <= e; i += 16) {
      u32 e0 = __builtin_nontemporal_load(&csr[i]);
      u32 e1 = __builtin_nontemporal_load(&csr[i + 1]);
      u32 e2 = __builtin_nontemporal_load(&csr[i + 2]);
      u32 e3 = __builtin_nontemporal_load(&csr[i + 3]);
      u32 e4 = __builtin_nontemporal_load(&csr[i + 4]);
      u32 e5 = __builtin_nontemporal_load(&csr[i + 5]);
      u32 e6 = __builtin_nontemporal_load(&csr[i + 6]);
      u32 e7 = __builtin_nontemporal_load(&csr[i + 7]);
      u32 e8 = __builtin_nontemporal_load(&csr[i + 8]);
      u32 e9 = __builtin_nontemporal_load(&csr[i + 9]);
      u32 ea0 = __builtin_nontemporal_load(&csr[i + 10]);
      u32 eb0 = __builtin_nontemporal_load(&csr[i + 11]);
      u32 ec0 = __builtin_nontemporal_load(&csr[i + 12]);
      u32 ed0 = __builtin_nontemporal_load(&csr[i + 13]);
      u32 ee0 = __builtin_nontemporal_load(&csr[i + 14]);
      u32 ef0 = __builtin_nontemporal_load(&csr[i + 15]);
      float v0 = 0.f, v1 = 0.f, v2 = 0.f, v3 = 0.f;
      float v4 = 0.f, v5 = 0.f, v6 = 0.f, v7 = 0.f;
      float v8 = 0.f, v9 = 0.f, va = 0.f, vb = 0.f;
      float vc = 0.f, vd = 0.f, ve = 0.f, vf = 0.f;
      if (act) {
        v0 = bf2f((u32)tin[(e0 >> 15) * FDIM + c]);
        v1 = bf2f((u32)tin[(e1 >> 15) * FDIM + c]);
        v2 = bf2f((u32)tin[(e2 >> 15) * FDIM + c]);
        v3 = bf2f((u32)tin[(e3 >> 15) * FDIM + c]);
        v4 = bf2f((u32)tin[(e4 >> 15) * FDIM + c]);
        v5 = bf2f((u32)tin[(e5 >> 15) * FDIM + c]);
        v6 = bf2f((u32)tin[(e6 >> 15) * FDIM + c]);
        v7 = bf2f((u32)tin[(e7 >> 15) * FDIM + c]);
        v8 = bf2f((u32)tin[(e8 >> 15) * FDIM + c]);
        v9 = bf2f((u32)tin[(e9 >> 15) * FDIM + c]);
        va = bf2f((u32)tin[(ea0 >> 15) * FDIM + c]);
        vb = bf2f((u32)tin[(eb0 >> 15) * FDIM + c]);
        vc = bf2f((u32)tin[(ec0 >> 15) * FDIM + c]);
        vd = bf2f((u32)tin[(ed0 >> 15) * FDIM + c]);
        ve = bf2f((u32)tin[(ee0 >> 15) * FDIM + c]);
        vf = bf2f((u32)tin[(ef0 >> 15) * FDIM + c]);
      }
      acc += bf2f(e0 & 0x7FFFu) * v0 + bf2f(e1 & 0x7FFFu) * v1 +
             bf2f(e2 & 0x7FFFu) * v2 + bf2f(e3 & 0x7FFFu) * v3 +
             bf2f(e4 & 0x7FFFu) * v4 + bf2f(e5 & 0x7FFFu) * v5 +
             bf2f(e6 & 0x7FFFu) * v6 + bf2f(e7 & 0x7FFFu) * v7 +
             bf2f(e8 & 0x7FFFu) * v8 + bf2f(e9 & 0x7FFFu) * v9 +
             bf2f(ea0 & 0x7FFFu) * va + bf2f(eb0 & 0x7FFFu) * vb +
             bf2f(ec0 & 0x7FFFu) * vc + bf2f(ed0 & 0x7FFFu) * vd +
             bf2f(ee0 & 0x7FFFu) * ve + bf2f(ef0 & 0x7FFFu) * vf;
    }
    for (; i + 8 <= e; i += 8) {
      u32 e0 = __builtin_nontemporal_load(&csr[i]);
      u32 e1 = __builtin_nontemporal_load(&csr[i + 1]);
      u32 e2 = __builtin_nontemporal_load(&csr[i + 2]);
      u32 e3 = __builtin_nontemporal_load(&csr[i + 3]);
      u32 e4 = __builtin_nontemporal_load(&csr[i + 4]);
      u32 e5 = __builtin_nontemporal_load(&csr[i + 5]);
      u32 e6 = __builtin_nontemporal_load(&csr[i + 6]);
      u32 e7 = __builtin_nontemporal_load(&csr[i + 7]);
      float v0 = 0.f, v1 = 0.f, v2 = 0.f, v3 = 0.f;
      float v4 = 0.f, v5 = 0.f, v6 = 0.f, v7 = 0.f;
      if (act) {
        v0 = bf2f((u32)tin[(e0 >> 15) * FDIM + c]);
        v1 = bf2f((u32)tin[(e1 >> 15) * FDIM + c]);
        v2 = bf2f((u32)tin[(e2 >> 15) * FDIM + c]);
        v3 = bf2f((u32)tin[(e3 >> 15) * FDIM + c]);
        v4 = bf2f((u32)tin[(e4 >> 15) * FDIM + c]);
        v5 = bf2f((u32)tin[(e5 >> 15) * FDIM + c]);
        v6 = bf2f((u32)tin[(e6 >> 15) * FDIM + c]);
        v7 = bf2f((u32)tin[(e7 >> 15) * FDIM + c]);
      }
      acc += bf2f(e0 & 0x7FFFu) * v0 + bf2f(e1 & 0x7FFFu) * v1 +
             bf2f(e2 & 0x7FFFu) * v2 + bf2f(e3 & 0x7FFFu) * v3 +
             bf2f(e4 & 0x7FFFu) * v4 + bf2f(e5 & 0x7FFFu) * v5 +
             bf2f(e6 & 0x7FFFu) * v6 + bf2f(e7 & 0x7FFFu) * v7;
    }
    for (; i + 4 <= e; i += 4) {
      u32 e0 = __builtin_nontemporal_load(&csr[i]);
      u32 e1 = __builtin_nontemporal_load(&csr[i + 1]);
      u32 e2 = __builtin_nontemporal_load(&csr[i + 2]);
      u32 e3 = __builtin_nontemporal_load(&csr[i + 3]);
      float v0 = 0.f, v1 = 0.f, v2 = 0.f, v3 = 0.f;
      if (act) {
        v0 = bf2f((u32)tin[(e0 >> 15) * FDIM + c]);
        v1 = bf2f((u32)tin[(e1 >> 15) * FDIM + c]);
        v2 = bf2f((u32)tin[(e2 >> 15) * FDIM + c]);
        v3 = bf2f((u32)tin[(e3 >> 15) * FDIM + c]);
      }
      acc += bf2f(e0 & 0x7FFFu) * v0 + bf2f(e1 & 0x7FFFu) * v1 +
             bf2f(e2 & 0x7FFFu) * v2 + bf2f(e3 & 0x7FFFu) * v3;
    }
    for (; i < e; ++i) {
      u32 ee = __builtin_nontemporal_load(&csr[i]);
      if (act) acc += bf2f(ee & 0x7FFFu) * bf2f((u32)tin[(ee >> 15) * FDIM + c]);
    }
    float dn = dinv[nu];
    float u = fmaxf(acc * dn + x[nu] * rb + bb, 0.f);
    if (do_t) {
      float tf = 0.f;
      int base = c & 48;
#pragma unroll
      for (int f = 0; f < 16; ++f) tf += __shfl(u, base + f, 64) * wreg[f];
      if (act) tout[(size_t)nu * FDIM + c] = f2bf(tf * dn);
    } else {
      float m1v = __shfl(u, lane + 16, 64);
      float m2v = __shfl(u, lane + 32, 64);
      if (lane < NH) hbuf[(size_t)nu * NH + lane] = (u + m1v + m2v) * (1.f / 3.f);
    }
  }
}

// ---------------- BN stats over hbuf [N,16] ---------------------------------
__global__ __launch_bounds__(256) void bn_stats_kernel(
    const float* __restrict__ h, double* __restrict__ stats) {
  __shared__ float ssum[NH], ssq[NH];
  int tid = threadIdx.x;
  if (tid < NH) { ssum[tid] = 0.f; ssq[tid] = 0.f; }
  __syncthreads();
  int n = blockIdx.x * blockDim.x + tid;
  bool valid = n < N_NODES;
  const float4* p = (const float4*)(h + (size_t)(valid ? n : 0) * NH);
  float hv[NH];
#pragma unroll
  for (int q = 0; q < 4; ++q) {
    float4 v = valid ? p[q] : make_float4(0.f, 0.f, 0.f, 0.f);
    hv[q * 4 + 0] = v.x; hv[q * 4 + 1] = v.y; hv[q * 4 + 2] = v.z; hv[q * 4 + 3] = v.w;
  }
#pragma unroll
  for (int f = 0; f < NH; ++f) {
    float s = hv[f], q = hv[f] * hv[f];
    for (int o = 32; o; o >>= 1) { s += __shfl_xor(s, o, 64); q += __shfl_xor(q, o, 64); }
    if ((tid & 63) == 0) { atomicAdd(&ssum[f], s); atomicAdd(&ssq[f], q); }
  }
  __syncthreads();
  if (tid < NH) {
    atomicAdd(&stats[tid], (double)ssum[tid]);
    atomicAdd(&stats[NH + tid], (double)ssq[tid]);
  }
}

__global__ __launch_bounds__(64) void bn_final_kernel(
    const double* __restrict__ stats, const float* __restrict__ g,
    const float* __restrict__ b, float* __restrict__ sc, float* __restrict__ sh) {
  int f = threadIdx.x;
  if (f < NH) {
    double mu = stats[f] / (double)N_NODES;
    double var = stats[NH + f] / (double)N_NODES - mu * mu;
    float scale = g[f] * (float)(1.0 / sqrt(var + (double)BN_EPS));
    sc[f] = scale;
    sh[f] = b[f] - (float)mu * scale;
  }
}

// ---------------- conv2 init: BN-apply + relu + init/root dots --------------
__global__ __launch_bounds__(256) void conv2_init_kernel(
    const float* __restrict__ h, const float* __restrict__ sc, const float* __restrict__ sh,
    const float* __restrict__ dinv,
    const float* __restrict__ w2i, const float* __restrict__ w2r, const float* __restrict__ b2,
    float* __restrict__ P, float* __restrict__ R) {
  int n = blockIdx.x * blockDim.x + threadIdx.x;
  if (n >= N_NODES) return;
  float u[NH];
#pragma unroll
  for (int f = 0; f < NH; ++f) u[f] = fmaxf(h[(size_t)n * NH + f] * sc[f] + sh[f], 0.f);
  float dn = dinv[n];
#pragma unroll
  for (int k = 0; k < 3; ++k) {
    float r = b2[k], o = 0.f;
#pragma unroll
    for (int f = 0; f < NH; ++f) {
      r += u[f] * w2r[k * NH + f];
      o += u[f] * w2i[k * NH + f];
    }
    R[n * 4 + k] = r;
    P[n * 4 + k] = o * dn;
  }
  R[n * 4 + 3] = 0.f;
  P[n * 4 + 3] = 0.f;
}

// ---------------- conv2 propagate: 16-lane groups, packed CSR ---------------
__global__ __launch_bounds__(256) void conv2_prop_kernel(
    const float* __restrict__ in4, float* __restrict__ out4, float* __restrict__ y,
    const u32* __restrict__ csr, const int* __restrict__ offs,
    const float* __restrict__ dinv,
    const float* __restrict__ R, const float* __restrict__ w2,
    int scale_w2, int final_out) {
  int t = blockIdx.x * 256 + threadIdx.x;
  int n = t >> 4, sub = t & 15;
  float m0 = 1.f, m1 = 1.f, m2 = 1.f;
  if (scale_w2) { m0 = w2[0]; m1 = w2[1]; m2 = w2[2]; }
  int s = offs[n], e = offs[n + 1];
  float a0 = 0.f, a1 = 0.f, a2 = 0.f;
  for (int i = s + sub; i < e; i += 16) {
    u32 ee = csr[i];
    float w = bf2f(ee & 0x7FFFu);
    const float4 v = *(const float4*)(in4 + (size_t)(ee >> 15) * 4);
    a0 += w * v.x;
    a1 += w * v.y;
    a2 += w * v.z;
  }
#pragma unroll
  for (int o = 8; o; o >>= 1) {
    a0 += __shfl_xor(a0, o, 64);
    a1 += __shfl_xor(a1, o, 64);
    a2 += __shfl_xor(a2, o, 64);
  }
  if (sub == 0) {
    float dn = dinv[n];
    a0 = a0 * dn * m0 + R[n * 4 + 0];
    a1 = a1 * dn * m1 + R[n * 4 + 1];
    a2 = a2 * dn * m2 + R[n * 4 + 2];
    if (final_out) {
      float sm = (a0 + a1 + a2) * (1.f / 3.f);
      y[n] = 1.f / (1.f + expf(-sm));
    } else {
      out4[n * 4 + 0] = a0 * dn;
      out4[n * 4 + 1] = a1 * dn;
      out4[n * 4 + 2] = a2 * dn;
      out4[n * 4 + 3] = 0.f;
    }
  }
}

extern "C" void kernel_launch(void* const* d_in, const int* in_sizes, int n_in,
                              void* d_out, int out_size, void* d_ws, size_t ws_size,
                              hipStream_t stream) {
  const float* x   = (const float*)d_in[0];
  const int*   ei  = (const int*)d_in[1];
  const float* ea  = (const float*)d_in[2];
  // d_in[3] = batch (unused)
  const float* w1i = (const float*)d_in[4];
  const float* w1  = (const float*)d_in[5];
  const float* w1r = (const float*)d_in[6];
  const float* b1  = (const float*)d_in[7];
  const float* bng = (const float*)d_in[8];
  const float* bnb = (const float*)d_in[9];
  const float* w2i = (const float*)d_in[10];
  const float* w2  = (const float*)d_in[11];
  const float* w2r = (const float*)d_in[12];
  const float* b2  = (const float*)d_in[13];
  float* y = (float*)d_out;

  const int* row = ei;
  const int* col = ei + N_EDGES;

  char* ws = (char*)d_ws;
  size_t off = 0;
  auto alloc = [&](size_t bytes) -> char* {
    char* p = ws + off;
    off += (bytes + 255) & ~(size_t)255;
    return p;
  };
  u32*    btot   = (u32*)alloc((size_t)NBUCK * 8 * 4);
  u32*    gcur   = (u32*)alloc((size_t)NBUCK * 8 * 4);
  u32*    bstart = (u32*)alloc((size_t)(NBUCK + 1) * 4);
  int*    offs   = (int*)alloc((size_t)(N_NODES + 1) * 4);
  float*  dinv   = (float*)alloc((size_t)N_NODES * 4);
  u16*    zx     = (u16*)alloc((size_t)N_NODES * 2);
  double* stats  = (double*)alloc(32 * 8);
  float*  bnsc   = (float*)alloc(16 * 4);
  float*  bnsh   = (float*)alloc(16 * 4);
  int2*   bucketed = (int2*)alloc((size_t)N_EDGES * 8);
  u32*    csr    = (u32*)alloc((size_t)N_EDGES * 4);
  u16*    tA     = (u16*)alloc((size_t)N_NODES * FDIM * 2);
  u16*    tB     = (u16*)alloc((size_t)N_NODES * FDIM * 2);
  float*  hbuf   = (float*)alloc((size_t)N_NODES * NH * 4);
  float*  P2     = (float*)alloc((size_t)N_NODES * 4 * 4);
  float*  Q2     = (float*)alloc((size_t)N_NODES * 4 * 4);
  float*  R2     = (float*)alloc((size_t)N_NODES * 4 * 4);
  (void)ws_size; (void)in_sizes; (void)n_in; (void)out_size;

  hipMemsetAsync(btot, 0, (size_t)NBUCK * 8 * 4, stream);
  hipMemsetAsync(stats, 0, 32 * 8, stream);

  bucket_count_kernel<<<NBLK1, 1024, 0, stream>>>(col, btot);
  bucket_scan_kernel<<<1, 256, 0, stream>>>(btot, bstart, gcur, offs);
  bucket_scatter_kernel<<<NBLK1, 1024, 0, stream>>>(row, col, ea, gcur, bucketed);
  node_offs_kernel<<<NBUCK, 1024, 0, stream>>>(bucketed, bstart, x, offs, dinv, zx);
  csr_fill_kernel<<<NBUCK, 1024, 0, stream>>>(bucketed, bstart, offs, csr);

  const int NPB = 6250;  // N_NODES*16/256 exactly
  // conv1 layer 1 (rank-1 collapse): merged scalar prop + dense epilogue -> tA
  sprop_mid_kernel<<<NPB, 256, 0, stream>>>(csr, offs, zx, dinv, x, w1i, w1r, b1, w1, tA);
  // conv1 layers 2-4: combined 3-stack propagation; 6250 blocks = 4 nodes/wave
  conv1_prop_kernel<<<6250, 256, 0, stream>>>(tA, tB, nullptr, csr, offs, dinv, x, w1r, b1, w1, 1);
  conv1_prop_kernel<<<6250, 256, 0, stream>>>(tB, tA, nullptr, csr, offs, dinv, x, w1r, b1, w1, 1);
  conv1_prop_kernel<<<6250, 256, 0, stream>>>(tA, nullptr, hbuf, csr, offs, dinv, x, w1r, b1, w1, 0);

  bn_stats_kernel<<<(N_NODES + 255) / 256, 256, 0, stream>>>(hbuf, stats);
  bn_final_kernel<<<1, 64, 0, stream>>>(stats, bng, bnb, bnsc, bnsh);
  conv2_init_kernel<<<(N_NODES + 255) / 256, 256, 0, stream>>>(
      hbuf, bnsc, bnsh, dinv, w2i, w2r, b2, P2, R2);

  conv2_prop_kernel<<<NPB, 256, 0, stream>>>(P2, Q2, nullptr, csr, offs, dinv, R2, w2, 0, 0);
  conv2_prop_kernel<<<NPB, 256, 0, stream>>>(Q2, P2, nullptr, csr, offs, dinv, R2, w2, 1, 0);
  conv2_prop_kernel<<<NPB, 256, 0, stream>>>(P2, Q2, nullptr, csr, offs, dinv, R2, w2, 1, 0);
  conv2_prop_kernel<<<NPB, 256, 0, stream>>>(Q2, P2, y, csr, offs, dinv, R2, w2, 1, 1);
}

// Round 16
// 488.225 us; speedup vs baseline: 1.7726x; 1.0115x over previous
//
#include <hip/hip_runtime.h>
#include <math.h>

#define N_NODES 100000
#define N_EDGES 3200000
#define KH 48            // K*H active channels
#define FDIM 64          // padded feature row stride (128 B, line-aligned)
#define NH 16            // H
#define BN_EPS 1e-5f
#define NBUCK 196        // ceil(100000/512) buckets of 512 nodes
#define BSHIFT 9
#define BMASK 511
#define EPB 16384        // edges per block in bucket scatter
#define NBLK1 196        // ceil(N_EDGES/EPB)
#define CAP 18432        // fixed bucket capacity: mean 16327 + 16 sigma
#define FIX 16777216.0f  // 2^24 fixed point for degree sums

typedef unsigned long long u64;
typedef unsigned int u32;
typedef unsigned short u16;

__device__ __forceinline__ u16 f2bf(float f) {
  u32 b = __float_as_uint(f);
  b += 0x7FFFu + ((b >> 16) & 1u);   // RNE
  return (u16)(b >> 16);
}
__device__ __forceinline__ float bf2f(u32 s) {
  return __uint_as_float(s << 16);
}

// ---------------- K1: scatter edges into FIXED-CAPACITY buckets -------------
// No pre-count needed: bucket b owns [b*CAP, b*CAP+fill). gcur[b*8] = fill.
__global__ __launch_bounds__(1024) void bucket_scatter_kernel(
    const int* __restrict__ row, const int* __restrict__ col,
    const float* __restrict__ ea, u32* __restrict__ gcur,
    int2* __restrict__ bucketed) {
  __shared__ u32 bins[NBUCK];
  __shared__ u32 base[NBUCK];
  __shared__ u16 rnk[EPB];
  for (int t = threadIdx.x; t < NBUCK; t += 1024) bins[t] = 0;
  __syncthreads();
  int eb = blockIdx.x * EPB;
  for (int it = 0; it < EPB / 1024; ++it) {
    int i = it * 1024 + threadIdx.x;
    int e = eb + i;
    if (e < N_EDGES) rnk[i] = (u16)atomicAdd(&bins[col[e] >> BSHIFT], 1u);
  }
  __syncthreads();
  for (int t = threadIdx.x; t < NBUCK; t += 1024) {
    u32 c = bins[t];
    if (c) base[t] = (u32)t * CAP + atomicAdd(&gcur[t * 8], c);
  }
  __syncthreads();
  for (int it = 0; it < EPB / 1024; ++it) {
    int i = it * 1024 + threadIdx.x;
    int e = eb + i;
    if (e < N_EDGES) {
      int c = col[e];
      int bkt = c >> BSHIFT, cl = c & BMASK;
      u32 pos = base[bkt] + (u32)rnk[i];
      bucketed[pos] = make_int2((cl << 17) | row[e], __float_as_int(ea[e]));
    }
  }
}

// ---------------- P2a: per-bucket node counts -> offs, dinv, zx -------------
// Computes its own compact bucket start (reduction over gcur) — no scan kernel.
__global__ __launch_bounds__(1024) void node_offs_kernel(
    const int2* __restrict__ bucketed, const u32* __restrict__ gcur,
    const float* __restrict__ x,
    int* __restrict__ offs, float* __restrict__ dinv, u16* __restrict__ zx) {
  __shared__ u32 cnt[512];
  __shared__ u32 degf[512];
  __shared__ u32 red[256];
  __shared__ u32 shmeta[2];   // [0]=bstart, [1]=fill
  int t = threadIdx.x;
  int b = blockIdx.x;
  if (t < 512) { cnt[t] = 0; degf[t] = 0; }
  if (t < 256) red[t] = (t < b) ? gcur[t * 8] : 0;   // NBUCK<256
  __syncthreads();
  for (int d = 128; d; d >>= 1) {
    if (t < d) red[t] += red[t + d];
    __syncthreads();
  }
  if (t == 0) { shmeta[0] = red[0]; shmeta[1] = gcur[b * 8]; }
  __syncthreads();
  u32 bst = shmeta[0], fill = shmeta[1];
  u32 s_pad = (u32)b * CAP;
  for (u32 i = t; i < fill; i += 1024) {
    int2 v = bucketed[s_pad + i];
    int cl = (v.x >> 17) & BMASK;
    atomicAdd(&cnt[cl], 1u);
    atomicAdd(&degf[cl], (u32)(__int_as_float(v.y) * FIX));
  }
  __syncthreads();
  u32 v0 = (t < 512) ? cnt[t] : 0;
  for (int d = 1; d < 512; d <<= 1) {
    u32 u = (t < 512 && t >= d) ? cnt[t - d] : 0;
    __syncthreads();
    if (t < 512) cnt[t] += u;
    __syncthreads();
  }
  int n = b * 512 + t;
  if (t < 512 && n < N_NODES) {
    offs[n] = (int)(bst + cnt[t] - v0);  // exclusive, compact
    float dg = (float)degf[t] * (1.0f / FIX);
    float dv = dg > 0.f ? rsqrtf(fmaxf(dg, 1e-12f)) : 0.f;
    dinv[n] = dv;
    zx[n] = f2bf(x[n] * dv);
  }
  if (b == 0 && t == 0) offs[N_NODES] = N_EDGES;
}

// ---------------- P2b: packed 4B CSR: (src<<15) | bf16(ea) ------------------
__global__ __launch_bounds__(1024) void csr_fill_kernel(
    const int2* __restrict__ bucketed, const u32* __restrict__ gcur,
    const int* __restrict__ offs, u32* __restrict__ csr) {
  __shared__ u32 cur[512];
  __shared__ u32 shfill;
  int t = threadIdx.x;
  int b = blockIdx.x;
  int n = b * 512 + t;
  if (t < 512) cur[t] = (n < N_NODES) ? (u32)offs[n] : 0;
  if (t == 0) shfill = gcur[b * 8];
  __syncthreads();
  u32 fill = shfill;
  u32 s_pad = (u32)b * CAP;
  for (u32 i = t; i < fill; i += 1024) {
    int2 v = bucketed[s_pad + i];
    int cl = (v.x >> 17) & BMASK;
    u32 r = (u32)(v.x & 0x1FFFF);
    u16 w = f2bf(__int_as_float(v.y));   // ea >= 0 -> sign bit 0, w < 0x8000
    u32 pos = atomicAdd(&cur[cl], 1u);
    csr[pos] = (r << 15) | (u32)w;
  }
}

// ---------------- layer-1: scalar prop + epilogue + transform (merged) ------
__global__ __launch_bounds__(256) void sprop_mid_kernel(
    const u32* __restrict__ csr, const int* __restrict__ offs,
    const u16* __restrict__ zx, const float* __restrict__ dinv,
    const float* __restrict__ x,
    const float* __restrict__ w1i, const float* __restrict__ w1r,
    const float* __restrict__ b1, const float* __restrict__ w1,
    u16* __restrict__ tout) {
  int t = blockIdx.x * 256 + threadIdx.x;
  int n = t >> 4, c = t & 15;
  float a = 0.f;
  int s = offs[n], e = offs[n + 1];
  for (int i = s + c; i < e; i += 16) {
    u32 ee = csr[i];
    a += bf2f(ee & 0x7FFFu) * bf2f((u32)zx[ee >> 15]);
  }
#pragma unroll
  for (int o = 8; o; o >>= 1) a += __shfl_xor(a, o, 64);
  float dn = dinv[n];
  float sn = a * dn;
  float xn = x[n];
  int base = (threadIdx.x & 63) & 48;
#pragma unroll
  for (int k = 0; k < 3; ++k) {
    float u = fmaxf(sn * w1i[k * 16 + c] + xn * w1r[k * 16 + c] + b1[k * 16 + c], 0.f);
    float tf = 0.f;
#pragma unroll
    for (int f = 0; f < 16; ++f) tf += __shfl(u, base + f, 64) * w1[k * 256 + f * 16 + c];
    tout[(size_t)n * FDIM + k * 16 + c] = f2bf(tf * dn);
  }
}

// ---------------- conv1 propagate, all 3 stacks combined --------------------
// wave per node, lane = channel, 48 active; rows 128 B line-aligned.
// EXPLICIT-SCALAR unroll-16 tier, then 8/4/scalar ladder. All unmasked.
__global__ __launch_bounds__(256) void conv1_prop_kernel(
    const u16* __restrict__ tin, u16* __restrict__ tout, float* __restrict__ hbuf,
    const u32* __restrict__ csr, const int* __restrict__ offs,
    const float* __restrict__ dinv, const float* __restrict__ x,
    const float* __restrict__ w1r, const float* __restrict__ b1,
    const float* __restrict__ w1, int do_t) {
  int lane = threadIdx.x & 63;
  int wid = (blockIdx.x * blockDim.x + threadIdx.x) >> 6;
  int nw = (gridDim.x * blockDim.x) >> 6;
  int c = lane;
  bool act = c < KH;
  float rb = act ? w1r[c] : 0.f;
  float bb = act ? b1[c] : 0.f;
  float wreg[16];
  if (do_t) {
    int k = c >> 4, o = c & 15;
    if (act) {
#pragma unroll
      for (int f = 0; f < 16; ++f) wreg[f] = w1[k * 256 + f * 16 + o];
    } else {
#pragma unroll
      for (int f = 0; f < 16; ++f) wreg[f] = 0.f;
    }
  }
  for (int n = wid; n < N_NODES; n += nw) {
    int nu = __builtin_amdgcn_readfirstlane(n);
    int s = offs[nu], e = offs[nu + 1];
    float acc = 0.f;
    int i = s;
    for (; i + 16 <= e; i += 16) {
      u32 e0 = __builtin_nontemporal_load(&csr[i]);
      u32 e1 = __builtin_nontemporal_load(&csr[i + 1]);
      u32 e2 = __builtin_nontemporal_load(&csr[i + 2]);
      u32 e3 = __builtin_nontemporal_load(&csr[i + 3]);
      u32 e4 = __builtin_nontemporal_load(&csr[i + 4]);
      u32 e5 = __builtin_nontemporal_load(&csr[i + 5]);
      u32 e6 = __builtin_nontemporal_load(&csr[i + 6]);
      u32 e7 = __builtin_nontemporal_load(&csr[i + 7]);
      u32 e8 = __builtin_nontemporal_load(&csr[i + 8]);
      u32 e9 = __builtin_nontemporal_load(&csr[i + 9]);
      u32 ea0 = __builtin_nontemporal_load(&csr[i + 10]);
      u32 eb0 = __builtin_nontemporal_load(&csr[i + 11]);
      u32 ec0 = __builtin_nontemporal_load(&csr[i + 12]);
      u32 ed0 = __builtin_nontemporal_load(&csr[i + 13]);
      u32 ee0 = __builtin_nontemporal_load(&csr[i + 14]);
      u32 ef0 = __builtin_nontemporal_load(&csr[i + 15]);
      float v0 = 0.f, v1 = 0.f, v2 = 0.f, v3 = 0.f;
      float v4 = 0.f, v5 = 0.f, v6 = 0.f, v7 = 0.f;
      float v8 = 0.f, v9 = 0.f, va = 0.f, vb = 0.f;
      float vc = 0.f, vd = 0.f, ve = 0.f, vf = 0.f;
      if (act) {
        v0 = bf2f((u32)tin[(e0 >> 15) * FDIM + c]);
        v1 = bf2f((u32)tin[(e1 >> 15) * FDIM + c]);
        v2 = bf2f((u32)tin[(e2 >> 15) * FDIM + c]);
        v3 = bf2f((u32)tin[(e3 >> 15) * FDIM + c]);
        v4 = bf2f((u32)tin[(e4 >> 15) * FDIM + c]);
        v5 = bf2f((u32)tin[(e5 >> 15) * FDIM + c]);
        v6 = bf2f((u32)tin[(e6 >> 15) * FDIM + c]);
        v7 = bf2f((u32)tin[(e7 >> 15) * FDIM + c]);
        v8 = bf2f((u32)tin[(e8 >> 15) * FDIM + c]);
        v9 = bf2f((u32)tin[(e9 >> 15) * FDIM + c]);
        va = bf2f((u32)tin[(ea0 >> 15) * FDIM + c]);
        vb = bf2f((u32)tin[(eb0 >> 15) * FDIM + c]);
        vc = bf2f((u32)tin[(ec0 >> 15) * FDIM + c]);
        vd = bf2f((u32)tin[(ed0 >> 15) * FDIM + c]);
        ve = bf2f((u32)tin[(ee0 >> 15) * FDIM + c]);
        vf = bf2f((u32)tin[(ef0 >> 15) * FDIM + c]);
      }
      acc += bf2f(e0 & 0x7FFFu) * v0 + bf2f(e1 & 0x7FFFu) * v1 +
             bf2f(e2 & 0x7FFFu) * v2 + bf2f(e3 & 0x7FFFu) * v3 +
             bf2f(e4 & 0x7FFFu) * v4 + bf2f(e5 & 0x7FFFu) * v5 +
             bf2f(e6 & 0x7FFFu) * v6 + bf2f(e7 & 0x7FFFu) * v7 +
             bf2f(e8 & 0x7FFFu) * v8 + bf2f(e9 & 0x7FFFu) * v9 +
             bf2f(ea0 & 0x7FFFu) * va + bf2f(eb0 & 0x7FFFu) * vb +
             bf2f(ec0 & 0x7FFFu) * vc + bf2f(ed0 & 0x7FFFu) * vd +
             bf2f(ee0 & 0x7FFFu) * ve + bf2f(ef0 & 0x7FFFu) * vf;
    }
    for (; i + 8 <= e; i += 8) {
      u32 e0 = __builtin_nontemporal_load(&csr[i]);
      u32 e1 = __builtin_nontemporal_load(&csr[i + 1]);
      u32 e2 = __builtin_nontemporal_load(&csr[i + 2]);
      u32 e3 = __builtin_nontemporal_load(&csr[i + 3]);
      u32 e4 = __builtin_nontemporal_load(&csr[i + 4]);
      u32 e5 = __builtin_nontemporal_load(&csr[i + 5]);
      u32 e6 = __builtin_nontemporal_load(&csr[i + 6]);
      u32 e7 = __builtin_nontemporal_load(&csr[i + 7]);
      float v0 = 0.f, v1 = 0.f, v2 = 0.f, v3 = 0.f;
      float v4 = 0.f, v5 = 0.f, v6 = 0.f, v7 = 0.f;
      if (act) {
        v0 = bf2f((u32)tin[(e0 >> 15) * FDIM + c]);
        v1 = bf2f((u32)tin[(e1 >> 15) * FDIM + c]);
        v2 = bf2f((u32)tin[(e2 >> 15) * FDIM + c]);
        v3 = bf2f((u32)tin[(e3 >> 15) * FDIM + c]);
        v4 = bf2f((u32)tin[(e4 >> 15) * FDIM + c]);
        v5 = bf2f((u32)tin[(e5 >> 15) * FDIM + c]);
        v6 = bf2f((u32)tin[(e6 >> 15) * FDIM + c]);
        v7 = bf2f((u32)tin[(e7 >> 15) * FDIM + c]);
      }
      acc += bf2f(e0 & 0x7FFFu) * v0 + bf2f(e1 & 0x7FFFu) * v1 +
             bf2f(e2 & 0x7FFFu) * v2 + bf2f(e3 & 0x7FFFu) * v3 +
             bf2f(e4 & 0x7FFFu) * v4 + bf2f(e5 & 0x7FFFu) * v5 +
             bf2f(e6 & 0x7FFFu) * v6 + bf2f(e7 & 0x7FFFu) * v7;
    }
    for (; i + 4 <= e; i += 4) {
      u32 e0 = __builtin_nontemporal_load(&csr[i]);
      u32 e1 = __builtin_nontemporal_load(&csr[i + 1]);
      u32 e2 = __builtin_nontemporal_load(&csr[i + 2]);
      u32 e3 = __builtin_nontemporal_load(&csr[i + 3]);
      float v0 = 0.f, v1 = 0.f, v2 = 0.f, v3 = 0.f;
      if (act) {
        v0 = bf2f((u32)tin[(e0 >> 15) * FDIM + c]);
        v1 = bf2f((u32)tin[(e1 >> 15) * FDIM + c]);
        v2 = bf2f((u32)tin[(e2 >> 15) * FDIM + c]);
        v3 = bf2f((u32)tin[(e3 >> 15) * FDIM + c]);
      }
      acc += bf2f(e0 & 0x7FFFu) * v0 + bf2f(e1 & 0x7FFFu) * v1 +
             bf2f(e2 & 0x7FFFu) * v2 + bf2f(e3 & 0x7FFFu) * v3;
    }
    for (; i < e; ++i) {
      u32 ee = __builtin_nontemporal_load(&csr[i]);
      if (act) acc += bf2f(ee & 0x7FFFu) * bf2f((u32)tin[(ee >> 15) * FDIM + c]);
    }
    float dn = dinv[nu];
    float u = fmaxf(acc * dn + x[nu] * rb + bb, 0.f);
    if (do_t) {
      float tf = 0.f;
      int base = c & 48;
#pragma unroll
      for (int f = 0; f < 16; ++f) tf += __shfl(u, base + f, 64) * wreg[f];
      if (act) tout[(size_t)nu * FDIM + c] = f2bf(tf * dn);
    } else {
      float m1v = __shfl(u, lane + 16, 64);
      float m2v = __shfl(u, lane + 32, 64);
      if (lane < NH) hbuf[(size_t)nu * NH + lane] = (u + m1v + m2v) * (1.f / 3.f);
    }
  }
}

// ---------------- BN stats over hbuf [N,16] ---------------------------------
__global__ __launch_bounds__(256) void bn_stats_kernel(
    const float* __restrict__ h, double* __restrict__ stats) {
  __shared__ float ssum[NH], ssq[NH];
  int tid = threadIdx.x;
  if (tid < NH) { ssum[tid] = 0.f; ssq[tid] = 0.f; }
  __syncthreads();
  int n = blockIdx.x * blockDim.x + tid;
  bool valid = n < N_NODES;
  const float4* p = (const float4*)(h + (size_t)(valid ? n : 0) * NH);
  float hv[NH];
#pragma unroll
  for (int q = 0; q < 4; ++q) {
    float4 v = valid ? p[q] : make_float4(0.f, 0.f, 0.f, 0.f);
    hv[q * 4 + 0] = v.x; hv[q * 4 + 1] = v.y; hv[q * 4 + 2] = v.z; hv[q * 4 + 3] = v.w;
  }
#pragma unroll
  for (int f = 0; f < NH; ++f) {
    float s = hv[f], q = hv[f] * hv[f];
    for (int o = 32; o; o >>= 1) { s += __shfl_xor(s, o, 64); q += __shfl_xor(q, o, 64); }
    if ((tid & 63) == 0) { atomicAdd(&ssum[f], s); atomicAdd(&ssq[f], q); }
  }
  __syncthreads();
  if (tid < NH) {
    atomicAdd(&stats[tid], (double)ssum[tid]);
    atomicAdd(&stats[NH + tid], (double)ssq[tid]);
  }
}

__global__ __launch_bounds__(64) void bn_final_kernel(
    const double* __restrict__ stats, const float* __restrict__ g,
    const float* __restrict__ b, float* __restrict__ sc, float* __restrict__ sh) {
  int f = threadIdx.x;
  if (f < NH) {
    double mu = stats[f] / (double)N_NODES;
    double var = stats[NH + f] / (double)N_NODES - mu * mu;
    float scale = g[f] * (float)(1.0 / sqrt(var + (double)BN_EPS));
    sc[f] = scale;
    sh[f] = b[f] - (float)mu * scale;
  }
}

// ---------------- conv2 init: BN-apply + relu + init/root dots --------------
__global__ __launch_bounds__(256) void conv2_init_kernel(
    const float* __restrict__ h, const float* __restrict__ sc, const float* __restrict__ sh,
    const float* __restrict__ dinv,
    const float* __restrict__ w2i, const float* __restrict__ w2r, const float* __restrict__ b2,
    float* __restrict__ P, float* __restrict__ R) {
  int n = blockIdx.x * blockDim.x + threadIdx.x;
  if (n >= N_NODES) return;
  float u[NH];
#pragma unroll
  for (int f = 0; f < NH; ++f) u[f] = fmaxf(h[(size_t)n * NH + f] * sc[f] + sh[f], 0.f);
  float dn = dinv[n];
#pragma unroll
  for (int k = 0; k < 3; ++k) {
    float r = b2[k], o = 0.f;
#pragma unroll
    for (int f = 0; f < NH; ++f) {
      r += u[f] * w2r[k * NH + f];
      o += u[f] * w2i[k * NH + f];
    }
    R[n * 4 + k] = r;
    P[n * 4 + k] = o * dn;
  }
  R[n * 4 + 3] = 0.f;
  P[n * 4 + 3] = 0.f;
}

// ---------------- conv2 propagate: 16-lane groups, packed CSR ---------------
__global__ __launch_bounds__(256) void conv2_prop_kernel(
    const float* __restrict__ in4, float* __restrict__ out4, float* __restrict__ y,
    const u32* __restrict__ csr, const int* __restrict__ offs,
    const float* __restrict__ dinv,
    const float* __restrict__ R, const float* __restrict__ w2,
    int scale_w2, int final_out) {
  int t = blockIdx.x * 256 + threadIdx.x;
  int n = t >> 4, sub = t & 15;
  float m0 = 1.f, m1 = 1.f, m2 = 1.f;
  if (scale_w2) { m0 = w2[0]; m1 = w2[1]; m2 = w2[2]; }
  int s = offs[n], e = offs[n + 1];
  float a0 = 0.f, a1 = 0.f, a2 = 0.f;
  for (int i = s + sub; i < e; i += 16) {
    u32 ee = csr[i];
    float w = bf2f(ee & 0x7FFFu);
    const float4 v = *(const float4*)(in4 + (size_t)(ee >> 15) * 4);
    a0 += w * v.x;
    a1 += w * v.y;
    a2 += w * v.z;
  }
#pragma unroll
  for (int o = 8; o; o >>= 1) {
    a0 += __shfl_xor(a0, o, 64);
    a1 += __shfl_xor(a1, o, 64);
    a2 += __shfl_xor(a2, o, 64);
  }
  if (sub == 0) {
    float dn = dinv[n];
    a0 = a0 * dn * m0 + R[n * 4 + 0];
    a1 = a1 * dn * m1 + R[n * 4 + 1];
    a2 = a2 * dn * m2 + R[n * 4 + 2];
    if (final_out) {
      float sm = (a0 + a1 + a2) * (1.f / 3.f);
      y[n] = 1.f / (1.f + expf(-sm));
    } else {
      out4[n * 4 + 0] = a0 * dn;
      out4[n * 4 + 1] = a1 * dn;
      out4[n * 4 + 2] = a2 * dn;
      out4[n * 4 + 3] = 0.f;
    }
  }
}

extern "C" void kernel_launch(void* const* d_in, const int* in_sizes, int n_in,
                              void* d_out, int out_size, void* d_ws, size_t ws_size,
                              hipStream_t stream) {
  const float* x   = (const float*)d_in[0];
  const int*   ei  = (const int*)d_in[1];
  const float* ea  = (const float*)d_in[2];
  // d_in[3] = batch (unused)
  const float* w1i = (const float*)d_in[4];
  const float* w1  = (const float*)d_in[5];
  const float* w1r = (const float*)d_in[6];
  const float* b1  = (const float*)d_in[7];
  const float* bng = (const float*)d_in[8];
  const float* bnb = (const float*)d_in[9];
  const float* w2i = (const float*)d_in[10];
  const float* w2  = (const float*)d_in[11];
  const float* w2r = (const float*)d_in[12];
  const float* b2  = (const float*)d_in[13];
  float* y = (float*)d_out;

  const int* row = ei;
  const int* col = ei + N_EDGES;

  char* ws = (char*)d_ws;
  size_t off = 0;
  auto alloc = [&](size_t bytes) -> char* {
    char* p = ws + off;
    off += (bytes + 255) & ~(size_t)255;
    return p;
  };
  u32*    gcur   = (u32*)alloc((size_t)NBUCK * 8 * 4);
  int*    offs   = (int*)alloc((size_t)(N_NODES + 1) * 4);
  float*  dinv   = (float*)alloc((size_t)N_NODES * 4);
  u16*    zx     = (u16*)alloc((size_t)N_NODES * 2);
  double* stats  = (double*)alloc(32 * 8);
  float*  bnsc   = (float*)alloc(16 * 4);
  float*  bnsh   = (float*)alloc(16 * 4);
  int2*   bucketed = (int2*)alloc((size_t)NBUCK * CAP * 8);
  u32*    csr    = (u32*)alloc((size_t)N_EDGES * 4);
  u16*    tA     = (u16*)alloc((size_t)N_NODES * FDIM * 2);
  u16*    tB     = (u16*)alloc((size_t)N_NODES * FDIM * 2);
  float*  hbuf   = (float*)alloc((size_t)N_NODES * NH * 4);
  float*  P2     = (float*)alloc((size_t)N_NODES * 4 * 4);
  float*  Q2     = (float*)alloc((size_t)N_NODES * 4 * 4);
  float*  R2     = (float*)alloc((size_t)N_NODES * 4 * 4);
  (void)ws_size; (void)in_sizes; (void)n_in; (void)out_size;

  hipMemsetAsync(gcur, 0, (size_t)NBUCK * 8 * 4, stream);
  hipMemsetAsync(stats, 0, 32 * 8, stream);

  bucket_scatter_kernel<<<NBLK1, 1024, 0, stream>>>(row, col, ea, gcur, bucketed);
  node_offs_kernel<<<NBUCK, 1024, 0, stream>>>(bucketed, gcur, x, offs, dinv, zx);
  csr_fill_kernel<<<NBUCK, 1024, 0, stream>>>(bucketed, gcur, offs, csr);

  const int NPB = 6250;  // N_NODES*16/256 exactly
  // conv1 layer 1 (rank-1 collapse): merged scalar prop + dense epilogue -> tA
  sprop_mid_kernel<<<NPB, 256, 0, stream>>>(csr, offs, zx, dinv, x, w1i, w1r, b1, w1, tA);
  // conv1 layers 2-4: combined 3-stack propagation; 6250 blocks = 4 nodes/wave
  conv1_prop_kernel<<<6250, 256, 0, stream>>>(tA, tB, nullptr, csr, offs, dinv, x, w1r, b1, w1, 1);
  conv1_prop_kernel<<<6250, 256, 0, stream>>>(tB, tA, nullptr, csr, offs, dinv, x, w1r, b1, w1, 1);
  conv1_prop_kernel<<<6250, 256, 0, stream>>>(tA, nullptr, hbuf, csr, offs, dinv, x, w1r, b1, w1, 0);

  bn_stats_kernel<<<(N_NODES + 255) / 256, 256, 0, stream>>>(hbuf, stats);
  bn_final_kernel<<<1, 64, 0, stream>>>(stats, bng, bnb, bnsc, bnsh);
  conv2_init_kernel<<<(N_NODES + 255) / 256, 256, 0, stream>>>(
      hbuf, bnsc, bnsh, dinv, w2i, w2r, b2, P2, R2);

  conv2_prop_kernel<<<NPB, 256, 0, stream>>>(P2, Q2, nullptr, csr, offs, dinv, R2, w2, 0, 0);
  conv2_prop_kernel<<<NPB, 256, 0, stream>>>(Q2, P2, nullptr, csr, offs, dinv, R2, w2, 1, 0);
  conv2_prop_kernel<<<NPB, 256, 0, stream>>>(P2, Q2, nullptr, csr, offs, dinv, R2, w2, 1, 0);
  conv2_prop_kernel<<<NPB, 256, 0, stream>>>(Q2, P2, y, csr, offs, dinv, R2, w2, 1, 1);
}